// Round 11
// baseline (326.937 us; speedup 1.0000x reference)
//
#include <hip/hip_runtime.h>
#include <hip/hip_bf16.h>
#include <stdint.h>

#define B_SZ 8192
#define D_SZ 1024
#define H_SZ 1024
#define O_SZ 512
#define E_SZ 8

typedef float f32x16 __attribute__((ext_vector_type(16)));
typedef __bf16 bf16x8 __attribute__((ext_vector_type(8)));

typedef __attribute__((address_space(1))) uint32_t gu32;
typedef __attribute__((address_space(3))) uint32_t lu32;

__device__ __forceinline__ unsigned short f2bf(float f) {
    union { __hip_bfloat16 h; unsigned short u; } c;
    c.h = __float2bfloat16(f);
    return c.u;
}
__device__ __forceinline__ float bf2f(unsigned short u) {
    union { float f; uint32_t u; } c;
    c.u = ((uint32_t)u) << 16;
    return c.f;
}

// Panel layout for GEMM operands: [panel=row>>8][kblk=k>>3][row&255][8 elems] bf16.
// 32x32x16 fragment reads are 32 lanes x 16 B contiguous -> zero bank conflicts.

// ------- fused: convert x -> panelized bf16 AND 20 gate logits + 3 softmaxes -------
__global__ __launch_bounds__(1024) void k_convert_gates(const float* __restrict__ x,
                                                        const float* __restrict__ Wg,
                                                        const float* __restrict__ Wgs,
                                                        unsigned short* __restrict__ x_kb,
                                                        float* __restrict__ g_all) {
    __shared__ unsigned short xs[16][D_SZ];   // 32 KiB
    const int wv = threadIdx.x >> 6;
    const int lane = threadIdx.x & 63;
    const int b0 = blockIdx.x * 16;
    const int b = b0 + wv;
    const float* xr = x + (size_t)b * D_SZ;
    float acc[20];
#pragma unroll
    for (int j = 0; j < 20; ++j) acc[j] = 0.f;
#pragma unroll 4
    for (int it = 0; it < 16; ++it) {
        const int d = it * 64 + lane;
        const float xv = xr[d];
        xs[wv][d] = f2bf(xv);
        const float* w0 = Wg + (size_t)d * 6;
        const float* w1 = Wg + (size_t)D_SZ * 6 + (size_t)d * 6;
        const float* ws = Wgs + (size_t)d * 8;
#pragma unroll
        for (int j = 0; j < 6; ++j) acc[j] += xv * w0[j];
#pragma unroll
        for (int j = 0; j < 6; ++j) acc[6 + j] += xv * w1[j];
#pragma unroll
        for (int j = 0; j < 8; ++j) acc[12 + j] += xv * ws[j];
    }
#pragma unroll
    for (int j = 0; j < 20; ++j) {
        float v = acc[j];
#pragma unroll
        for (int s = 32; s > 0; s >>= 1) v += __shfl_down(v, s, 64);
        acc[j] = v;
    }
    if (lane == 0) {
        float* g = g_all + (size_t)b * 20;
#pragma unroll
        for (int t = 0; t < 3; ++t) {
            int base = (t == 0) ? 0 : (t == 1 ? 6 : 12);
            int cnt  = (t == 2) ? 8 : 6;
            float m = -1e30f;
            for (int j = 0; j < cnt; ++j) m = fmaxf(m, acc[base + j]);
            float ex[8]; float sum = 0.f;
            for (int j = 0; j < cnt; ++j) { ex[j] = __expf(acc[base + j] - m); sum += ex[j]; }
            float inv = 1.f / sum;
            for (int j = 0; j < cnt; ++j) g[base + j] = ex[j] * inv;
        }
    }
    __syncthreads();
    const char* lb = (const char*)&xs[0][0];
#pragma unroll
    for (int p = 0; p < 2; ++p) {
        const int u = p * 1024 + threadIdx.x;
        const int kblk = u >> 4, r16 = u & 15;
        int4 v = *(const int4*)(lb + r16 * 2048 + kblk * 16);
        *(int4*)(x_kb + (size_t)(b0 >> 8) * (D_SZ * 256) + (size_t)kblk * 2048
                 + ((b0 & 255) + r16) * 8) = v;
    }
}

// ------- transpose+convert+panelize: in [E][R][C] f32 -> panel[C>>8][R/8][c&255][8] bf16 -------
__global__ __launch_bounds__(512) void k_transpose_panel(const float* __restrict__ in,
                                                         unsigned short* __restrict__ out,
                                                         int R, int C) {
    __shared__ float tile[64][65];
    const float* src = in + (size_t)blockIdx.z * R * C;
    unsigned short* dst = out + (size_t)blockIdx.z * R * C;
    int c0 = blockIdx.x * 64, r0 = blockIdx.y * 64;
    int tx = threadIdx.x, ty = threadIdx.y;   // block (64,8)
#pragma unroll
    for (int rr = ty; rr < 64; rr += 8)
        tile[rr][tx] = src[(size_t)(r0 + rr) * C + c0 + tx];
    __syncthreads();
    union { ushort4 h[2]; int4 q; } u;
#pragma unroll
    for (int s = 0; s < 8; ++s)
        ((unsigned short*)&u)[s] = f2bf(tile[ty * 8 + s][tx]);
    const int c = c0 + tx;
    *(int4*)(dst + (size_t)(c >> 8) * (R * 256) + (size_t)((r0 >> 3) + ty) * 2048
             + (c & 255) * 8) = u.q;
}

// ------- 256x256 bf16 GEMM: 32x32x16 MFMA, panel LDS, RING-2 (64 KiB -> 2 blocks/CU) -------
// C = relu(A * Bt^T + bias). 512 thr = 8 waves (2M x 4N); wave 128x64 = acc[4][2] f32x16.
// LDS 64 KiB = 2 buffers x 32 KiB { A [4kblk][256][16B], B same @+16KiB }.
// Per tile: P1 {read aL(t); lgkmcnt(0); barrier; stage(t+2); 8 MFMA U(t)}
//           P2 {vmcnt(4); barrier; read aU/b(t+1); 8 MFMA L(t)}
// WAR: lgkmcnt(0)+barrier in P1 proves every wave's reads of buf[t&1] (incl. prior-P2
//      reads) completed before stage(t+2) rewrites it.
// RAW: vmcnt(4) leaves only stage(t+2) in flight -> t+1 landed; barrier makes it global.
// Tails: stage skipped when t+2>=NT; vmcnt->0. Epilogue: C staged via LDS in two
// 64-KiB halves (wr=0 rows, then wr=1) -> coalesced dwordx4 stores.
template <bool PANEL_OUT>
__global__ __launch_bounds__(512, 2) void k_gemm_r2(
    const unsigned short* __restrict__ A,
    const unsigned short* __restrict__ Bt,
    const float* __restrict__ bias,
    unsigned short* __restrict__ C,
    int M, int N, int K,
    long long sA, long long sB, long long sBias, long long sC, int e_base) {

    const int tid = threadIdx.x;
    const int lane = tid & 63, wid = tid >> 6;
    const int wr = wid >> 2, wc = wid & 3;       // 2 x 4 wave grid
    const int lr32 = lane & 31, hi = lane >> 5;

    // bijective XCD swizzle on flat grid (nwg % 8 == 0 for all launches here)
    const int nwg = gridDim.x;
    const int wg = blockIdx.x;
    const int swz = (wg & 7) * (nwg >> 3) + (wg >> 3);
    const int nx = N >> 8;
    const int my = M >> 8;
    const int bx = swz % nx;
    const int t1 = swz / nx;
    const int by = t1 % my;
    const int e  = t1 / my + e_base;

    A    += (size_t)((long long)e * sA);
    Bt   += (size_t)((long long)e * sB);
    bias += (size_t)((long long)e * sBias);
    C    += (size_t)((long long)e * sC);

    const int m0 = by * 256, n0 = bx * 256;

    __shared__ __align__(16) unsigned short lds[32768];   // 64 KiB
    char* ldsb = (char*)lds;

    const int skb = tid >> 8;         // 0/1
    const int srw = tid & 255;

    auto stageA = [&](int tt) {
        const int bb = (tt & 1) * 32768;
        const unsigned short* s0 = A + (size_t)(m0 >> 8) * K * 256
                                     + (size_t)(tt * 4 + skb) * 2048 + srw * 8;
        __builtin_amdgcn_global_load_lds((gu32*)s0, (lu32*)(ldsb + bb + tid * 16), 16, 0, 0);
        __builtin_amdgcn_global_load_lds((gu32*)(s0 + 4096),
                                         (lu32*)(ldsb + bb + 8192 + tid * 16), 16, 0, 0);
    };
    auto stageB = [&](int tt) {
        const int bb = (tt & 1) * 32768 + 16384;
        const unsigned short* s0 = Bt + (size_t)(n0 >> 8) * K * 256
                                      + (size_t)(tt * 4 + skb) * 2048 + srw * 8;
        __builtin_amdgcn_global_load_lds((gu32*)s0, (lu32*)(ldsb + bb + tid * 16), 16, 0, 0);
        __builtin_amdgcn_global_load_lds((gu32*)(s0 + 4096),
                                         (lu32*)(ldsb + bb + 8192 + tid * 16), 16, 0, 0);
    };

    // fragment byte offsets (zero-conflict contiguous 512 B per frag read)
    const int abase = (wr * 128 + lr32) * 16 + hi * 4096;
    const int bbase = 16384 + (wc * 64 + lr32) * 16 + hi * 4096;

    auto readA = [&](bf16x8* d, int bb, int mb) {
#pragma unroll
        for (int q = 0; q < 4; ++q) {
            const int mi = mb + (q >> 1), s = q & 1;
            d[q] = *(const bf16x8*)(ldsb + bb + abase + mi * 512 + s * 8192);
        }
    };
    auto readB = [&](bf16x8* d, int bb) {
#pragma unroll
        for (int q = 0; q < 4; ++q) {
            const int nj = q >> 1, s = q & 1;
            d[q] = *(const bf16x8*)(ldsb + bb + bbase + nj * 512 + s * 8192);
        }
    };

    f32x16 acc[4][2];
#pragma unroll
    for (int i = 0; i < 4; ++i)
#pragma unroll
        for (int j = 0; j < 2; ++j)
            acc[i][j] = (f32x16)(0.f);

    auto mfma8 = [&](const bf16x8* fa, const bf16x8* fb, int rb) {
        __builtin_amdgcn_s_setprio(1);
#pragma unroll
        for (int i = 0; i < 2; ++i)
#pragma unroll
            for (int j = 0; j < 2; ++j)
#pragma unroll
                for (int s = 0; s < 2; ++s)
                    acc[rb + i][j] = __builtin_amdgcn_mfma_f32_32x32x16_bf16(
                        fa[i * 2 + s], fb[j * 2 + s], acc[rb + i][j], 0, 0, 0);
        __builtin_amdgcn_s_setprio(0);
    };

    const int NT = K >> 5;   // even, >= 4

    // prologue: stage tiles 0,1 (8 glds); vmcnt(4) -> tile 0 landed; read tile-0 U+B
    stageA(0); stageB(0); stageA(1); stageB(1);
    asm volatile("s_waitcnt vmcnt(4)" ::: "memory");
    asm volatile("s_barrier" ::: "memory");

    bf16x8 aU0[4], aL0[4], b0[4], aU1[4], aL1[4], b1v[4];
    readA(aU0, 0, 0); readB(b0, 0);

    for (int t = 0; t < NT; t += 2) {
        // ======== tile t (buf 0) ========
        // P1: last reads of buf0; prove-drain; restage buf0 with tile t+2; MFMA U(t)
        readA(aL0, 0, 2);
        asm volatile("s_waitcnt lgkmcnt(0)" ::: "memory");
        asm volatile("s_barrier" ::: "memory");
        if (t + 2 < NT) { stageA(t + 2); stageB(t + 2); }
        mfma8(aU0, b0, 0);
        // P2: tile t+1 landed; read its U+B; MFMA L(t)
        if (t + 2 < NT) { asm volatile("s_waitcnt vmcnt(4)" ::: "memory"); }
        else            { asm volatile("s_waitcnt vmcnt(0)" ::: "memory"); }
        asm volatile("s_barrier" ::: "memory");
        readA(aU1, 32768, 0); readB(b1v, 32768);
        mfma8(aL0, b0, 2);

        // ======== tile t+1 (buf 1) ========
        // P1: last reads of buf1; prove-drain; restage buf1 with tile t+3; MFMA U(t+1)
        readA(aL1, 32768, 2);
        asm volatile("s_waitcnt lgkmcnt(0)" ::: "memory");
        asm volatile("s_barrier" ::: "memory");
        if (t + 3 < NT) { stageA(t + 3); stageB(t + 3); }
        mfma8(aU1, b1v, 0);
        // P2: tile t+2 landed; read its U+B (into the 0-register set); MFMA L(t+1)
        if (t + 3 < NT) { asm volatile("s_waitcnt vmcnt(4)" ::: "memory"); }
        else            { asm volatile("s_waitcnt vmcnt(0)" ::: "memory"); }
        asm volatile("s_barrier" ::: "memory");
        if (t + 2 < NT) { readA(aU0, 0, 0); readB(b0, 0); }
        mfma8(aL1, b1v, 2);
    }

    // ---- epilogue: two 64-KiB halves through LDS -> coalesced stores ----
    __syncthreads();
#pragma unroll
    for (int h = 0; h < 2; ++h) {
        if (wr == h) {
#pragma unroll
            for (int nj = 0; nj < 2; ++nj) {
                const int nn = wc * 64 + nj * 32 + lr32;
                const float bv = bias[n0 + nn];
#pragma unroll
                for (int mi = 0; mi < 4; ++mi) {
#pragma unroll
                    for (int r = 0; r < 16; ++r) {
                        const int ml = mi * 32 + (r & 3) + 8 * (r >> 2) + 4 * hi;  // 0..127
                        float v = fmaxf(acc[mi][nj][r] + bv, 0.f);
                        if (PANEL_OUT) {
                            const int pu = (nn >> 3) ^ (ml & 7);
                            *(unsigned short*)(ldsb + ml * 512 + pu * 16 + (nn & 7) * 2) = f2bf(v);
                        } else {
                            *(unsigned short*)(ldsb + ml * 512 + nn * 2) = f2bf(v);
                        }
                    }
                }
            }
        }
        __syncthreads();
        if (PANEL_OUT) {
#pragma unroll
            for (int it = 0; it < 8; ++it) {
                const int u = it * 512 + tid;
                const int blk = u >> 8, row = u & 255;   // blk 0..15 local? u<4096: blk 0..15
                int4 v = *(const int4*)(ldsb + (row & 127) * 512
                                        + (((blk * 2 + (row >> 7)) ^ ((row & 127) & 7)) * 16));
                // NOTE: decode below mirrors write: half rows 0..127, 32 units/row
                (void)v;
            }
            // simple exact readout: 4096 int4 units = 128 rows x 32 units
#pragma unroll
            for (int it = 0; it < 8; ++it) {
                const int u = it * 512 + tid;
                const int row = u >> 5, blk = u & 31;
                int4 v = *(const int4*)(ldsb + row * 512 + ((blk ^ (row & 7)) * 16));
                *(int4*)(C + (size_t)(m0 >> 8) * N * 256 + (size_t)((n0 >> 3) + blk) * 2048
                         + (h * 128 + row + (m0 & 255)) * 8) = v;
            }
        } else {
#pragma unroll
            for (int it = 0; it < 8; ++it) {
                const int u = it * 512 + tid;
                const int row = u >> 5, blk = u & 31;
                *(int4*)(&C[(size_t)(m0 + h * 128 + row) * N + n0 + blk * 8]) =
                    *(const int4*)(ldsb + row * 512 + blk * 16);
            }
        }
        __syncthreads();
    }
}

// ---------------- combine: out[b][t][o], 4 o's per thread (eo row-major) ----------------
__global__ __launch_bounds__(256) void k_combine(const unsigned short* __restrict__ eo,
                                                 const float* __restrict__ g_all,
                                                 float* __restrict__ out) {
    int idx4 = blockIdx.x * 256 + threadIdx.x;    // over B*O/4
    int b = idx4 >> 7;                            // O/4 = 128
    int o4 = (idx4 & 127) * 4;
    const float* g = g_all + (size_t)b * 20;
    float v[E_SZ][4];
#pragma unroll
    for (int e = 0; e < E_SZ; ++e) {
        ushort4 u = *(const ushort4*)(eo + (size_t)e * B_SZ * O_SZ + (size_t)b * O_SZ + o4);
        v[e][0] = bf2f(u.x); v[e][1] = bf2f(u.y); v[e][2] = bf2f(u.z); v[e][3] = bf2f(u.w);
    }
    float4 r0, r1, r2;
    float* p0 = (float*)&r0; float* p1 = (float*)&r1; float* p2 = (float*)&r2;
#pragma unroll
    for (int c = 0; c < 4; ++c) {
        p0[c] = g[0] * v[0][c] + g[1] * v[1][c] + g[2] * v[4][c] + g[3] * v[5][c]
              + g[4] * v[6][c] + g[5] * v[7][c];
        p1[c] = g[6] * v[2][c] + g[7] * v[3][c] + g[8] * v[4][c] + g[9] * v[5][c]
              + g[10] * v[6][c] + g[11] * v[7][c];
        float s = 0.f;
#pragma unroll
        for (int e = 0; e < E_SZ; ++e) s += g[12 + e] * v[e][c];
        p2[c] = s;
    }
    size_t ob = (size_t)b * (3 * O_SZ) + o4;
    *(float4*)(out + ob) = r0;
    *(float4*)(out + ob + O_SZ) = r1;
    *(float4*)(out + ob + 2 * O_SZ) = r2;
}

extern "C" void kernel_launch(void* const* d_in, const int* in_sizes, int n_in,
                              void* d_out, int out_size, void* d_ws, size_t ws_size,
                              hipStream_t stream) {
    const float* x   = (const float*)d_in[0];
    const float* W1  = (const float*)d_in[1];
    const float* b1  = (const float*)d_in[2];
    const float* W2  = (const float*)d_in[3];
    const float* b2  = (const float*)d_in[4];
    const float* Wg  = (const float*)d_in[5];
    const float* Wgs = (const float*)d_in[6];
    float* out = (float*)d_out;

    char* ws = (char*)d_ws;
    const size_t SZ_XBF  = (size_t)B_SZ * D_SZ * 2;           // 16 MB (panelized)
    const size_t SZ_W1T  = (size_t)E_SZ * H_SZ * D_SZ * 2;    // 16 MB (panelized)
    const size_t SZ_W2T  = (size_t)E_SZ * O_SZ * H_SZ * 2;    // 8 MB  (panelized)
    const size_t SZ_EO   = (size_t)E_SZ * B_SZ * O_SZ * 2;    // 64 MB (row-major)
    const size_t SZ_G    = (size_t)B_SZ * 20 * 4;             // 640 KB
    const size_t SZ_HBIG = (size_t)E_SZ * B_SZ * H_SZ * 2;    // 128 MB (panelized)

    unsigned short* x_kb = (unsigned short*)ws;              ws += SZ_XBF;
    unsigned short* W1T  = (unsigned short*)ws;              ws += SZ_W1T;
    unsigned short* W2T  = (unsigned short*)ws;              ws += SZ_W2T;
    unsigned short* eo   = (unsigned short*)ws;              ws += SZ_EO;
    float* g_all         = (float*)ws;                       ws += SZ_G;
    unsigned short* h_buf = (unsigned short*)ws;

    const size_t fixed = SZ_XBF + SZ_W1T + SZ_W2T + SZ_EO + SZ_G;
    const bool big = ws_size >= fixed + SZ_HBIG;

    // 1) fused convert(panelize) + gates; panelizing weight transposes
    k_convert_gates<<<B_SZ / 16, 1024, 0, stream>>>(x, Wg, Wgs, x_kb, g_all);
    dim3 tb(64, 8);
    k_transpose_panel<<<dim3(H_SZ / 64, D_SZ / 64, E_SZ), tb, 0, stream>>>(W1, W1T, D_SZ, H_SZ);
    k_transpose_panel<<<dim3(O_SZ / 64, H_SZ / 64, E_SZ), tb, 0, stream>>>(W2, W2T, H_SZ, O_SZ);

    // 2) expert GEMMs (256x256 tiles; flat 1D grids, all % 8 == 0)
    if (big) {
        k_gemm_r2<true><<<(H_SZ / 256) * (B_SZ / 256) * E_SZ, 512, 0, stream>>>(
            x_kb, W1T, b1, h_buf, B_SZ, H_SZ, D_SZ,
            0LL, (long long)H_SZ * D_SZ, (long long)H_SZ, (long long)B_SZ * H_SZ, 0);
        k_gemm_r2<false><<<(O_SZ / 256) * (B_SZ / 256) * E_SZ, 512, 0, stream>>>(
            h_buf, W2T, b2, eo, B_SZ, O_SZ, H_SZ,
            (long long)B_SZ * H_SZ, (long long)O_SZ * H_SZ, (long long)O_SZ, (long long)B_SZ * O_SZ, 0);
    } else {
        for (int e = 0; e < E_SZ; ++e) {
            k_gemm_r2<true><<<(H_SZ / 256) * (B_SZ / 256), 512, 0, stream>>>(
                x_kb, W1T, b1, h_buf, B_SZ, H_SZ, D_SZ,
                0LL, (long long)H_SZ * D_SZ, (long long)H_SZ, 0LL, e);
            k_gemm_r2<false><<<(O_SZ / 256) * (B_SZ / 256), 512, 0, stream>>>(
                h_buf, W2T, b2, eo, B_SZ, O_SZ, H_SZ,
                0LL, (long long)O_SZ * H_SZ, (long long)O_SZ, (long long)B_SZ * O_SZ, e);
        }
    }

    // 3) combine
    k_combine<<<(B_SZ * O_SZ / 4) / 256, 256, 0, stream>>>(eo, g_all, out);
}

// Round 12
// 305.341 us; speedup vs baseline: 1.0707x; 1.0707x over previous
//
#include <hip/hip_runtime.h>
#include <hip/hip_bf16.h>
#include <stdint.h>

#define B_SZ 8192
#define D_SZ 1024
#define H_SZ 1024
#define O_SZ 512
#define E_SZ 8

typedef float f32x4 __attribute__((ext_vector_type(4)));
typedef __bf16 bf16x8 __attribute__((ext_vector_type(8)));

typedef __attribute__((address_space(1))) uint32_t gu32;
typedef __attribute__((address_space(3))) uint32_t lu32;

__device__ __forceinline__ unsigned short f2bf(float f) {
    union { __hip_bfloat16 h; unsigned short u; } c;
    c.h = __float2bfloat16(f);
    return c.u;
}
__device__ __forceinline__ float bf2f(unsigned short u) {
    union { float f; uint32_t u; } c;
    c.u = ((uint32_t)u) << 16;
    return c.f;
}

// ------- fused: convert x row to bf16 AND 20 gate logits + 3 softmaxes -------
// 16 waves/block, one x-row per wave. Gate weights staged ONCE per block in LDS
// (padded to 21 floats/row: gcd(21,32)=1 -> conflict-free strided lane reads),
// cutting gate-weight L2 re-read traffic 16x (640 MB -> 41 MB).
__global__ __launch_bounds__(1024) void k_convert_gates(const float* __restrict__ x,
                                                        const float* __restrict__ Wg,
                                                        const float* __restrict__ Wgs,
                                                        unsigned short* __restrict__ x_bf,
                                                        float* __restrict__ g_all) {
    __shared__ float wlds[D_SZ * 21];   // 84 KiB
    const int wv = threadIdx.x >> 6;
    const int lane = threadIdx.x & 63;
    const int b = blockIdx.x * 16 + wv;

    // stage gate weights: 20480 elements, 20 per thread
#pragma unroll
    for (int p = 0; p < 20; ++p) {
        const int e = p * 1024 + threadIdx.x;
        const int d = e / 20, j = e % 20;
        float v;
        if (j < 6)       v = Wg[(size_t)d * 6 + j];
        else if (j < 12) v = Wg[(size_t)D_SZ * 6 + (size_t)d * 6 + (j - 6)];
        else             v = Wgs[(size_t)d * 8 + (j - 12)];
        wlds[d * 21 + j] = v;
    }
    __syncthreads();

    const float* xr = x + (size_t)b * D_SZ;
    unsigned short* xo = x_bf + (size_t)b * D_SZ;
    float acc[20];
#pragma unroll
    for (int j = 0; j < 20; ++j) acc[j] = 0.f;
#pragma unroll 4
    for (int it = 0; it < 16; ++it) {
        const int d = it * 64 + lane;
        const float xv = xr[d];
        xo[d] = f2bf(xv);
        const float* w = &wlds[d * 21];
#pragma unroll
        for (int j = 0; j < 20; ++j) acc[j] += xv * w[j];
    }
#pragma unroll
    for (int j = 0; j < 20; ++j) {
        float v = acc[j];
#pragma unroll
        for (int s = 32; s > 0; s >>= 1) v += __shfl_down(v, s, 64);
        acc[j] = v;
    }
    if (lane == 0) {
        float* g = g_all + (size_t)b * 20;
#pragma unroll
        for (int t = 0; t < 3; ++t) {
            int base = (t == 0) ? 0 : (t == 1 ? 6 : 12);
            int cnt  = (t == 2) ? 8 : 6;
            float m = -1e30f;
            for (int j = 0; j < cnt; ++j) m = fmaxf(m, acc[base + j]);
            float ex[8]; float sum = 0.f;
            for (int j = 0; j < cnt; ++j) { ex[j] = __expf(acc[base + j] - m); sum += ex[j]; }
            float inv = 1.f / sum;
            for (int j = 0; j < cnt; ++j) g[base + j] = ex[j] * inv;
        }
    }
}

// ------- transpose+convert: in [E][R][C] f32 -> out [E][C][R] bf16 -------
__global__ __launch_bounds__(512) void k_transpose_convert(const float* __restrict__ in,
                                                           unsigned short* __restrict__ out,
                                                           int R, int C) {
    __shared__ float tile[64][65];
    const float* src = in + (size_t)blockIdx.z * R * C;
    unsigned short* dst = out + (size_t)blockIdx.z * R * C;
    int c0 = blockIdx.x * 64, r0 = blockIdx.y * 64;
    int tx = threadIdx.x, ty = threadIdx.y;   // block (64,8)
#pragma unroll
    for (int rr = ty; rr < 64; rr += 8)
        tile[rr][tx] = src[(size_t)(r0 + rr) * C + c0 + tx];
    __syncthreads();
#pragma unroll
    for (int rr = ty; rr < 64; rr += 8)
        dst[(size_t)(c0 + rr) * R + r0 + tx] = f2bf(tile[tx][rr]);
}

// ------- 256x256 bf16 GEMM: ring-4 BK=32 + one-phase-ahead fragment pipeline -------
// (round-9 verified fastest: G1 = 147.4 us, 931 TF)
// C[M][N] = relu(A[M][K] * Bt[N][K]^T + bias), bf16 in/out, f32 accum.
// 512 thr = 8 waves (2M x 4N); per-wave 128x64 out, acc[8][4] f32x4.
// LDS 128 KiB = 4 ring K-tile buffers x 32 KiB { A 256x32, B 256x32 }.
// RAW: reads of buf t+1 come after a barrier preceded by every wave's vmcnt(4);
// WAR: stage(t+3/t+4) is post-barrier, after consuming MFMAs drained reads.
// Swizzle: phys 16B block = blk ^ ((row>>1)&3); linear glds dest + inverse-swz source.
__global__ __launch_bounds__(512, 2) void k_gemm_pipe(
    const unsigned short* __restrict__ A,
    const unsigned short* __restrict__ Bt,
    const float* __restrict__ bias,
    unsigned short* __restrict__ C,
    int M, int N, int K,
    long long sA, long long sB, long long sBias, long long sC, int e_base) {

    const int tid = threadIdx.x;
    const int lane = tid & 63, wid = tid >> 6;
    const int wr = wid >> 2, wc = wid & 3;       // 2 x 4 wave grid
    const int lr = lane & 15, lg = lane >> 4;

    // bijective XCD swizzle on flat grid (nwg % 8 == 0 for all launches here)
    const int nwg = gridDim.x;
    const int wg = blockIdx.x;
    const int swz = (wg & 7) * (nwg >> 3) + (wg >> 3);
    const int nx = N >> 8;
    const int my = M >> 8;
    const int bx = swz % nx;
    const int t1 = swz / nx;
    const int by = t1 % my;
    const int e  = t1 / my + e_base;

    A    += (size_t)((long long)e * sA);
    Bt   += (size_t)((long long)e * sB);
    bias += (size_t)((long long)e * sBias);
    C    += (size_t)((long long)e * sC);

    const int m0 = by * 256, n0 = bx * 256;

    __shared__ __align__(16) unsigned short lds[65536];   // 128 KiB
    char* ldsb = (char*)lds;

    const int srow = tid >> 2;
    const int scol = (((tid & 3) ^ ((tid >> 3) & 3)) * 8);
    const int sdst = tid * 16;

    auto stageA2 = [&](int t) {   // A halves
        const int bb = (t & 3) * 32768;
        const unsigned short* s0 = A + (size_t)(m0 + srow) * K + (t << 5) + scol;
        __builtin_amdgcn_global_load_lds((gu32*)s0, (lu32*)(ldsb + bb + sdst), 16, 0, 0);
        __builtin_amdgcn_global_load_lds((gu32*)(s0 + (size_t)128 * K),
                                         (lu32*)(ldsb + bb + 8192 + sdst), 16, 0, 0);
    };
    auto stageB2 = [&](int t) {   // B halves
        const int bb = (t & 3) * 32768 + 16384;
        const unsigned short* s0 = Bt + (size_t)(n0 + srow) * K + (t << 5) + scol;
        __builtin_amdgcn_global_load_lds((gu32*)s0, (lu32*)(ldsb + bb + sdst), 16, 0, 0);
        __builtin_amdgcn_global_load_lds((gu32*)(s0 + (size_t)128 * K),
                                         (lu32*)(ldsb + bb + 8192 + sdst), 16, 0, 0);
    };

    const int cblk = (lg ^ ((lr >> 1) & 3)) * 16;
    const int aoff = wr * 8192 + lr * 64 + cblk;
    const int boff = 16384 + (wc >> 1) * 8192 + (wc & 1) * 4096 + lr * 64 + cblk;

    f32x4 acc[8][4];
#pragma unroll
    for (int i = 0; i < 8; ++i)
#pragma unroll
        for (int j = 0; j < 4; ++j)
            acc[i][j] = f32x4{0.f, 0.f, 0.f, 0.f};

    auto mfma16 = [&](const bf16x8 (&fa)[4], const bf16x8 (&fb)[4], int rbase) {
        __builtin_amdgcn_s_setprio(1);
#pragma unroll
        for (int i = 0; i < 4; ++i)
#pragma unroll
            for (int j = 0; j < 4; ++j)
                acc[rbase + i][j] = __builtin_amdgcn_mfma_f32_16x16x32_bf16(
                    fa[i], fb[j], acc[rbase + i][j], 0, 0, 0);
        __builtin_amdgcn_s_setprio(0);
    };

    const int NT = K >> 5;   // 32 (even)

    stageA2(0); stageB2(0); stageA2(1); stageB2(1); stageA2(2); stageB2(2);
    asm volatile("s_waitcnt vmcnt(8)" ::: "memory");
    asm volatile("s_barrier" ::: "memory");

    bf16x8 aU0[4], aL0[4], b0[4], aU1[4], aL1[4], b1v[4];
#pragma unroll
    for (int i = 0; i < 4; ++i) aU0[i] = *(const bf16x8*)(ldsb + aoff + i * 1024);
#pragma unroll
    for (int j = 0; j < 4; ++j) b0[j]  = *(const bf16x8*)(ldsb + boff + j * 1024);

    for (int t = 0; t < NT; t += 2) {
        const int bb0 = (t & 3) * 32768;
        const int bb1 = ((t + 1) & 3) * 32768;
        const int bb2 = ((t + 2) & 3) * 32768;

        // ---- phase (t,U): read L-frags(t); ensure t+1 landed; MFMA U(t) ----
#pragma unroll
        for (int i = 0; i < 4; ++i) aL0[i] = *(const bf16x8*)(ldsb + bb0 + aoff + (4 + i) * 1024);
        if (t + 2 < NT) { asm volatile("s_waitcnt vmcnt(4)" ::: "memory"); }
        else            { asm volatile("s_waitcnt vmcnt(0)" ::: "memory"); }
        asm volatile("s_barrier" ::: "memory");
        if (t + 3 < NT) stageA2(t + 3);
        mfma16(aU0, b0, 0);

        // ---- phase (t,L): read U-frags(t+1); MFMA L(t) ----
#pragma unroll
        for (int i = 0; i < 4; ++i) aU1[i] = *(const bf16x8*)(ldsb + bb1 + aoff + i * 1024);
#pragma unroll
        for (int j = 0; j < 4; ++j) b1v[j] = *(const bf16x8*)(ldsb + bb1 + boff + j * 1024);
        asm volatile("s_barrier" ::: "memory");
        if (t + 3 < NT) stageB2(t + 3);
        mfma16(aL0, b0, 4);

        // ---- phase (t+1,U): read L-frags(t+1); ensure t+2 landed; MFMA U(t+1) ----
#pragma unroll
        for (int i = 0; i < 4; ++i) aL1[i] = *(const bf16x8*)(ldsb + bb1 + aoff + (4 + i) * 1024);
        if (t + 3 < NT) { asm volatile("s_waitcnt vmcnt(4)" ::: "memory"); }
        else            { asm volatile("s_waitcnt vmcnt(0)" ::: "memory"); }
        asm volatile("s_barrier" ::: "memory");
        if (t + 4 < NT) stageA2(t + 4);
        mfma16(aU1, b1v, 0);

        // ---- phase (t+1,L): read U-frags(t+2); MFMA L(t+1) ----
        if (t + 2 < NT) {
#pragma unroll
            for (int i = 0; i < 4; ++i) aU0[i] = *(const bf16x8*)(ldsb + bb2 + aoff + i * 1024);
#pragma unroll
            for (int j = 0; j < 4; ++j) b0[j]  = *(const bf16x8*)(ldsb + bb2 + boff + j * 1024);
        }
        asm volatile("s_barrier" ::: "memory");
        if (t + 4 < NT) stageB2(t + 4);
        mfma16(aL1, b1v, 4);
    }

    // ---- epilogue: full drain, then bias+relu -> LDS tile -> coalesced stores ----
    __syncthreads();
    unsigned short* ct = (unsigned short*)ldsb;
#pragma unroll
    for (int j = 0; j < 4; ++j) {
        const int nn = wc * 64 + j * 16 + lr;
        const float bv = bias[n0 + nn];
#pragma unroll
        for (int i = 0; i < 8; ++i) {
            const int mb = wr * 128 + i * 16 + lg * 4;
#pragma unroll
            for (int r = 0; r < 4; ++r) {
                float v = fmaxf(acc[i][j][r] + bv, 0.f);
                ct[(size_t)(mb + r) * 256 + nn] = f2bf(v);
            }
        }
    }
    __syncthreads();
#pragma unroll
    for (int it = 0; it < 16; ++it) {
        const int row = it * 16 + (tid >> 5);
        const int colE = (tid & 31) * 8;
        *(int4*)(&C[(size_t)(m0 + row) * N + n0 + colE]) =
            *(const int4*)(ldsb + it * 8192 + (size_t)tid * 16);
    }
}

// ---------------- combine: out[b][t][o], 4 o's per thread ----------------
__global__ __launch_bounds__(256) void k_combine(const unsigned short* __restrict__ eo,
                                                 const float* __restrict__ g_all,
                                                 float* __restrict__ out) {
    int idx4 = blockIdx.x * 256 + threadIdx.x;    // over B*O/4
    int b = idx4 >> 7;                            // O/4 = 128
    int o4 = (idx4 & 127) * 4;
    const float* g = g_all + (size_t)b * 20;
    float v[E_SZ][4];
#pragma unroll
    for (int e = 0; e < E_SZ; ++e) {
        ushort4 u = *(const ushort4*)(eo + (size_t)e * B_SZ * O_SZ + (size_t)b * O_SZ + o4);
        v[e][0] = bf2f(u.x); v[e][1] = bf2f(u.y); v[e][2] = bf2f(u.z); v[e][3] = bf2f(u.w);
    }
    float4 r0, r1, r2;
    float* p0 = (float*)&r0; float* p1 = (float*)&r1; float* p2 = (float*)&r2;
#pragma unroll
    for (int c = 0; c < 4; ++c) {
        p0[c] = g[0] * v[0][c] + g[1] * v[1][c] + g[2] * v[4][c] + g[3] * v[5][c]
              + g[4] * v[6][c] + g[5] * v[7][c];
        p1[c] = g[6] * v[2][c] + g[7] * v[3][c] + g[8] * v[4][c] + g[9] * v[5][c]
              + g[10] * v[6][c] + g[11] * v[7][c];
        float s = 0.f;
#pragma unroll
        for (int e = 0; e < E_SZ; ++e) s += g[12 + e] * v[e][c];
        p2[c] = s;
    }
    size_t ob = (size_t)b * (3 * O_SZ) + o4;
    *(float4*)(out + ob) = r0;
    *(float4*)(out + ob + O_SZ) = r1;
    *(float4*)(out + ob + 2 * O_SZ) = r2;
}

extern "C" void kernel_launch(void* const* d_in, const int* in_sizes, int n_in,
                              void* d_out, int out_size, void* d_ws, size_t ws_size,
                              hipStream_t stream) {
    const float* x   = (const float*)d_in[0];
    const float* W1  = (const float*)d_in[1];
    const float* b1  = (const float*)d_in[2];
    const float* W2  = (const float*)d_in[3];
    const float* b2  = (const float*)d_in[4];
    const float* Wg  = (const float*)d_in[5];
    const float* Wgs = (const float*)d_in[6];
    float* out = (float*)d_out;

    char* ws = (char*)d_ws;
    const size_t SZ_XBF  = (size_t)B_SZ * D_SZ * 2;           // 16 MB
    const size_t SZ_W1T  = (size_t)E_SZ * H_SZ * D_SZ * 2;    // 16 MB
    const size_t SZ_W2T  = (size_t)E_SZ * O_SZ * H_SZ * 2;    // 8 MB
    const size_t SZ_EO   = (size_t)E_SZ * B_SZ * O_SZ * 2;    // 64 MB
    const size_t SZ_G    = (size_t)B_SZ * 20 * 4;             // 640 KB
    const size_t SZ_HBIG = (size_t)E_SZ * B_SZ * H_SZ * 2;    // 128 MB

    unsigned short* x_bf = (unsigned short*)ws;              ws += SZ_XBF;
    unsigned short* W1T  = (unsigned short*)ws;              ws += SZ_W1T;
    unsigned short* W2T  = (unsigned short*)ws;              ws += SZ_W2T;
    unsigned short* eo   = (unsigned short*)ws;              ws += SZ_EO;
    float* g_all         = (float*)ws;                       ws += SZ_G;
    unsigned short* h_buf = (unsigned short*)ws;

    const size_t fixed = SZ_XBF + SZ_W1T + SZ_W2T + SZ_EO + SZ_G;
    const bool big = ws_size >= fixed + SZ_HBIG;

    // 1) fused convert + gates (LDS-staged gate weights); weight transposes
    k_convert_gates<<<B_SZ / 16, 1024, 0, stream>>>(x, Wg, Wgs, x_bf, g_all);
    dim3 tb(64, 8);
    k_transpose_convert<<<dim3(H_SZ / 64, D_SZ / 64, E_SZ), tb, 0, stream>>>(W1, W1T, D_SZ, H_SZ);
    k_transpose_convert<<<dim3(O_SZ / 64, H_SZ / 64, E_SZ), tb, 0, stream>>>(W2, W2T, H_SZ, O_SZ);

    // 2) expert GEMMs (256x256 tiles; flat 1D grids, all % 8 == 0)
    if (big) {
        k_gemm_pipe<<<(H_SZ / 256) * (B_SZ / 256) * E_SZ, 512, 0, stream>>>(
            x_bf, W1T, b1, h_buf, B_SZ, H_SZ, D_SZ,
            0LL, (long long)H_SZ * D_SZ, (long long)H_SZ, (long long)B_SZ * H_SZ, 0);
        k_gemm_pipe<<<(O_SZ / 256) * (B_SZ / 256) * E_SZ, 512, 0, stream>>>(
            h_buf, W2T, b2, eo, B_SZ, O_SZ, H_SZ,
            (long long)B_SZ * H_SZ, (long long)O_SZ * H_SZ, (long long)O_SZ, (long long)B_SZ * O_SZ, 0);
    } else {
        for (int e = 0; e < E_SZ; ++e) {
            k_gemm_pipe<<<(H_SZ / 256) * (B_SZ / 256), 512, 0, stream>>>(
                x_bf, W1T, b1, h_buf, B_SZ, H_SZ, D_SZ,
                0LL, (long long)H_SZ * D_SZ, (long long)H_SZ, 0LL, e);
            k_gemm_pipe<<<(O_SZ / 256) * (B_SZ / 256), 512, 0, stream>>>(
                h_buf, W2T, b2, eo, B_SZ, O_SZ, H_SZ,
                0LL, (long long)O_SZ * H_SZ, (long long)O_SZ, (long long)B_SZ * O_SZ, e);
        }
    }

    // 3) combine
    k_combine<<<(B_SZ * O_SZ / 4) / 256, 256, 0, stream>>>(eo, g_all, out);
}

// Round 13
// 303.153 us; speedup vs baseline: 1.0785x; 1.0072x over previous
//
#include <hip/hip_runtime.h>
#include <hip/hip_bf16.h>
#include <stdint.h>

#define B_SZ 8192
#define D_SZ 1024
#define H_SZ 1024
#define O_SZ 512
#define E_SZ 8

typedef float f32x4 __attribute__((ext_vector_type(4)));
typedef __bf16 bf16x8 __attribute__((ext_vector_type(8)));

typedef __attribute__((address_space(1))) uint32_t gu32;
typedef __attribute__((address_space(3))) uint32_t lu32;

__device__ __forceinline__ unsigned short f2bf(float f) {
    union { __hip_bfloat16 h; unsigned short u; } c;
    c.h = __float2bfloat16(f);
    return c.u;
}
__device__ __forceinline__ float bf2f(unsigned short u) {
    union { float f; uint32_t u; } c;
    c.u = ((uint32_t)u) << 16;
    return c.f;
}

// ---------------- convert x (f32 -> bf16), 8 elems/thread ----------------
__global__ __launch_bounds__(256) void k_convert(const float* __restrict__ in,
                                                 unsigned short* __restrict__ out, int n8) {
    int i = blockIdx.x * 256 + threadIdx.x;
    if (i >= n8) return;
    const float4* p = (const float4*)in + (size_t)i * 2;
    float4 a = p[0], b = p[1];
    ushort4 lo, hi;
    lo.x = f2bf(a.x); lo.y = f2bf(a.y); lo.z = f2bf(a.z); lo.w = f2bf(a.w);
    hi.x = f2bf(b.x); hi.y = f2bf(b.y); hi.z = f2bf(b.z); hi.w = f2bf(b.w);
    ushort4* q = (ushort4*)out + (size_t)i * 2;
    q[0] = lo; q[1] = hi;
}

// ------- merged transpose+convert for W1 (z<8) and W2 (z>=8) -------
// in [E][R][C] f32 -> out [E][C][R] bf16. W1: R=C=1024; W2: R=1024, C=512.
__global__ __launch_bounds__(512) void k_transpose_both(const float* __restrict__ W1,
                                                        unsigned short* __restrict__ W1T,
                                                        const float* __restrict__ W2,
                                                        unsigned short* __restrict__ W2T) {
    const int z = blockIdx.z;
    const float* in; unsigned short* out; int R, C, e;
    if (z < 8) { in = W1; out = W1T; R = D_SZ; C = H_SZ; e = z; }
    else       { in = W2; out = W2T; R = H_SZ; C = O_SZ; e = z - 8;
                 if ((int)blockIdx.x >= C / 64) return; }   // block-uniform early out
    __shared__ float tile[64][65];
    const float* src = in + (size_t)e * R * C;
    unsigned short* dst = out + (size_t)e * R * C;
    int c0 = blockIdx.x * 64, r0 = blockIdx.y * 64;
    int tx = threadIdx.x, ty = threadIdx.y;   // block (64,8)
#pragma unroll
    for (int rr = ty; rr < 64; rr += 8)
        tile[rr][tx] = src[(size_t)(r0 + rr) * C + c0 + tx];
    __syncthreads();
#pragma unroll
    for (int rr = ty; rr < 64; rr += 8)
        dst[(size_t)(c0 + rr) * R + r0 + tx] = f2bf(tile[tx][rr]);
}

// ------- gates via MFMA: logits = x_bf @ WgAll^T (24 padded cols), then 3 softmaxes -------
// 256 blocks x 32 rows. 4 waves: wave w -> row-tile (w>>1), j-tile (w&1).
// B staged as WgT_lds[j][k] bf16, row stride 1032 elems (2064 B, 16B-aligned).
// Fragment conventions identical to the verified GEMMs: A row=lr,k=lg*8;
// C/D col=lr, row=lg*4+reg.
__global__ __launch_bounds__(256) void k_gates_mfma(const unsigned short* __restrict__ x_bf,
                                                    const float* __restrict__ Wg,
                                                    const float* __restrict__ Wgs,
                                                    float* __restrict__ g_all) {
    __shared__ unsigned short wlds[32 * 1032];   // 66 KiB
    __shared__ float logits[32][24];
    const int tid = threadIdx.x;

    // stage WgT (j-major), zero-pad j = 20..31
    for (int idx = tid; idx < 32 * 1024; idx += 256) {
        const int j = idx >> 10, k = idx & 1023;
        float v = 0.f;
        if (j < 6)       v = Wg[(size_t)k * 6 + j];
        else if (j < 12) v = Wg[(size_t)D_SZ * 6 + (size_t)k * 6 + (j - 6)];
        else if (j < 20) v = Wgs[(size_t)k * 8 + (j - 12)];
        wlds[j * 1032 + k] = f2bf(v);
    }
    __syncthreads();

    const int lane = tid & 63, w = tid >> 6;
    const int rt = w >> 1, jt = w & 1;
    const int lr = lane & 15, lg = lane >> 4;
    const int row0 = blockIdx.x * 32 + rt * 16;

    const unsigned short* xr = x_bf + (size_t)(row0 + lr) * D_SZ;
    const unsigned short* wrow = &wlds[(jt * 16 + lr) * 1032];

    f32x4 acc = f32x4{0.f, 0.f, 0.f, 0.f};
#pragma unroll 4
    for (int kt = 0; kt < 32; ++kt) {
        bf16x8 a = *(const bf16x8*)(xr + kt * 32 + lg * 8);
        bf16x8 b = *(const bf16x8*)(wrow + kt * 32 + lg * 8);
        acc = __builtin_amdgcn_mfma_f32_16x16x32_bf16(a, b, acc, 0, 0, 0);
    }
    const int j = jt * 16 + lr;
    if (j < 24) {
#pragma unroll
        for (int r = 0; r < 4; ++r)
            logits[rt * 16 + lg * 4 + r][j] = acc[r];
    }
    __syncthreads();

    if (tid < 32) {
        const int row = tid;
        float* g = g_all + (size_t)(blockIdx.x * 32 + row) * 20;
#pragma unroll
        for (int t = 0; t < 3; ++t) {
            const int base = (t == 0) ? 0 : (t == 1 ? 6 : 12);
            const int cnt  = (t == 2) ? 8 : 6;
            float m = -1e30f;
            for (int q = 0; q < cnt; ++q) m = fmaxf(m, logits[row][base + q]);
            float ex[8]; float sum = 0.f;
            for (int q = 0; q < cnt; ++q) { ex[q] = __expf(logits[row][base + q] - m); sum += ex[q]; }
            float inv = 1.f / sum;
            for (int q = 0; q < cnt; ++q) g[base + q] = ex[q] * inv;
        }
    }
}

// ------- 256x256 bf16 GEMM: ring-4 BK=32 + one-phase-ahead fragment pipeline -------
// (round-9/12 verified fastest: G1 = 147.5 us, 931 TF) — UNCHANGED.
__global__ __launch_bounds__(512, 2) void k_gemm_pipe(
    const unsigned short* __restrict__ A,
    const unsigned short* __restrict__ Bt,
    const float* __restrict__ bias,
    unsigned short* __restrict__ C,
    int M, int N, int K,
    long long sA, long long sB, long long sBias, long long sC, int e_base) {

    const int tid = threadIdx.x;
    const int lane = tid & 63, wid = tid >> 6;
    const int wr = wid >> 2, wc = wid & 3;       // 2 x 4 wave grid
    const int lr = lane & 15, lg = lane >> 4;

    const int nwg = gridDim.x;
    const int wg = blockIdx.x;
    const int swz = (wg & 7) * (nwg >> 3) + (wg >> 3);
    const int nx = N >> 8;
    const int my = M >> 8;
    const int bx = swz % nx;
    const int t1 = swz / nx;
    const int by = t1 % my;
    const int e  = t1 / my + e_base;

    A    += (size_t)((long long)e * sA);
    Bt   += (size_t)((long long)e * sB);
    bias += (size_t)((long long)e * sBias);
    C    += (size_t)((long long)e * sC);

    const int m0 = by * 256, n0 = bx * 256;

    __shared__ __align__(16) unsigned short lds[65536];   // 128 KiB
    char* ldsb = (char*)lds;

    const int srow = tid >> 2;
    const int scol = (((tid & 3) ^ ((tid >> 3) & 3)) * 8);
    const int sdst = tid * 16;

    auto stageA2 = [&](int t) {
        const int bb = (t & 3) * 32768;
        const unsigned short* s0 = A + (size_t)(m0 + srow) * K + (t << 5) + scol;
        __builtin_amdgcn_global_load_lds((gu32*)s0, (lu32*)(ldsb + bb + sdst), 16, 0, 0);
        __builtin_amdgcn_global_load_lds((gu32*)(s0 + (size_t)128 * K),
                                         (lu32*)(ldsb + bb + 8192 + sdst), 16, 0, 0);
    };
    auto stageB2 = [&](int t) {
        const int bb = (t & 3) * 32768 + 16384;
        const unsigned short* s0 = Bt + (size_t)(n0 + srow) * K + (t << 5) + scol;
        __builtin_amdgcn_global_load_lds((gu32*)s0, (lu32*)(ldsb + bb + sdst), 16, 0, 0);
        __builtin_amdgcn_global_load_lds((gu32*)(s0 + (size_t)128 * K),
                                         (lu32*)(ldsb + bb + 8192 + sdst), 16, 0, 0);
    };

    const int cblk = (lg ^ ((lr >> 1) & 3)) * 16;
    const int aoff = wr * 8192 + lr * 64 + cblk;
    const int boff = 16384 + (wc >> 1) * 8192 + (wc & 1) * 4096 + lr * 64 + cblk;

    f32x4 acc[8][4];
#pragma unroll
    for (int i = 0; i < 8; ++i)
#pragma unroll
        for (int j = 0; j < 4; ++j)
            acc[i][j] = f32x4{0.f, 0.f, 0.f, 0.f};

    auto mfma16 = [&](const bf16x8 (&fa)[4], const bf16x8 (&fb)[4], int rbase) {
        __builtin_amdgcn_s_setprio(1);
#pragma unroll
        for (int i = 0; i < 4; ++i)
#pragma unroll
            for (int j = 0; j < 4; ++j)
                acc[rbase + i][j] = __builtin_amdgcn_mfma_f32_16x16x32_bf16(
                    fa[i], fb[j], acc[rbase + i][j], 0, 0, 0);
        __builtin_amdgcn_s_setprio(0);
    };

    const int NT = K >> 5;

    stageA2(0); stageB2(0); stageA2(1); stageB2(1); stageA2(2); stageB2(2);
    asm volatile("s_waitcnt vmcnt(8)" ::: "memory");
    asm volatile("s_barrier" ::: "memory");

    bf16x8 aU0[4], aL0[4], b0[4], aU1[4], aL1[4], b1v[4];
#pragma unroll
    for (int i = 0; i < 4; ++i) aU0[i] = *(const bf16x8*)(ldsb + aoff + i * 1024);
#pragma unroll
    for (int j = 0; j < 4; ++j) b0[j]  = *(const bf16x8*)(ldsb + boff + j * 1024);

    for (int t = 0; t < NT; t += 2) {
        const int bb0 = (t & 3) * 32768;
        const int bb1 = ((t + 1) & 3) * 32768;
        const int bb2 = ((t + 2) & 3) * 32768;

#pragma unroll
        for (int i = 0; i < 4; ++i) aL0[i] = *(const bf16x8*)(ldsb + bb0 + aoff + (4 + i) * 1024);
        if (t + 2 < NT) { asm volatile("s_waitcnt vmcnt(4)" ::: "memory"); }
        else            { asm volatile("s_waitcnt vmcnt(0)" ::: "memory"); }
        asm volatile("s_barrier" ::: "memory");
        if (t + 3 < NT) stageA2(t + 3);
        mfma16(aU0, b0, 0);

#pragma unroll
        for (int i = 0; i < 4; ++i) aU1[i] = *(const bf16x8*)(ldsb + bb1 + aoff + i * 1024);
#pragma unroll
        for (int j = 0; j < 4; ++j) b1v[j] = *(const bf16x8*)(ldsb + bb1 + boff + j * 1024);
        asm volatile("s_barrier" ::: "memory");
        if (t + 3 < NT) stageB2(t + 3);
        mfma16(aL0, b0, 4);

#pragma unroll
        for (int i = 0; i < 4; ++i) aL1[i] = *(const bf16x8*)(ldsb + bb1 + aoff + (4 + i) * 1024);
        if (t + 3 < NT) { asm volatile("s_waitcnt vmcnt(4)" ::: "memory"); }
        else            { asm volatile("s_waitcnt vmcnt(0)" ::: "memory"); }
        asm volatile("s_barrier" ::: "memory");
        if (t + 4 < NT) stageA2(t + 4);
        mfma16(aU1, b1v, 0);

        if (t + 2 < NT) {
#pragma unroll
            for (int i = 0; i < 4; ++i) aU0[i] = *(const bf16x8*)(ldsb + bb2 + aoff + i * 1024);
#pragma unroll
            for (int j = 0; j < 4; ++j) b0[j]  = *(const bf16x8*)(ldsb + bb2 + boff + j * 1024);
        }
        asm volatile("s_barrier" ::: "memory");
        if (t + 4 < NT) stageB2(t + 4);
        mfma16(aL1, b1v, 4);
    }

    __syncthreads();
    unsigned short* ct = (unsigned short*)ldsb;
#pragma unroll
    for (int j = 0; j < 4; ++j) {
        const int nn = wc * 64 + j * 16 + lr;
        const float bv = bias[n0 + nn];
#pragma unroll
        for (int i = 0; i < 8; ++i) {
            const int mb = wr * 128 + i * 16 + lg * 4;
#pragma unroll
            for (int r = 0; r < 4; ++r) {
                float v = fmaxf(acc[i][j][r] + bv, 0.f);
                ct[(size_t)(mb + r) * 256 + nn] = f2bf(v);
            }
        }
    }
    __syncthreads();
#pragma unroll
    for (int it = 0; it < 16; ++it) {
        const int row = it * 16 + (tid >> 5);
        const int colE = (tid & 31) * 8;
        *(int4*)(&C[(size_t)(m0 + row) * N + n0 + colE]) =
            *(const int4*)(ldsb + it * 8192 + (size_t)tid * 16);
    }
}

// ---------------- combine: out[b][t][o], 8 o's per thread ----------------
__global__ __launch_bounds__(256) void k_combine(const unsigned short* __restrict__ eo,
                                                 const float* __restrict__ g_all,
                                                 float* __restrict__ out) {
    int idx8 = blockIdx.x * 256 + threadIdx.x;    // over B*O/8
    int b = idx8 >> 6;                            // O/8 = 64
    int o8 = (idx8 & 63) * 8;
    const float* g = g_all + (size_t)b * 20;
    float v[E_SZ][8];
#pragma unroll
    for (int e = 0; e < E_SZ; ++e) {
        const unsigned short* p = eo + (size_t)e * B_SZ * O_SZ + (size_t)b * O_SZ + o8;
        int4 u = *(const int4*)p;
        const unsigned short* us = (const unsigned short*)&u;
#pragma unroll
        for (int c = 0; c < 8; ++c) v[e][c] = bf2f(us[c]);
    }
    float r0[8], r1[8], r2[8];
#pragma unroll
    for (int c = 0; c < 8; ++c) {
        r0[c] = g[0] * v[0][c] + g[1] * v[1][c] + g[2] * v[4][c] + g[3] * v[5][c]
              + g[4] * v[6][c] + g[5] * v[7][c];
        r1[c] = g[6] * v[2][c] + g[7] * v[3][c] + g[8] * v[4][c] + g[9] * v[5][c]
              + g[10] * v[6][c] + g[11] * v[7][c];
        float s = 0.f;
#pragma unroll
        for (int e = 0; e < E_SZ; ++e) s += g[12 + e] * v[e][c];
        r2[c] = s;
    }
    size_t ob = (size_t)b * (3 * O_SZ) + o8;
    *(float4*)(out + ob)             = *(float4*)&r0[0];
    *(float4*)(out + ob + 4)         = *(float4*)&r0[4];
    *(float4*)(out + ob + O_SZ)      = *(float4*)&r1[0];
    *(float4*)(out + ob + O_SZ + 4)  = *(float4*)&r1[4];
    *(float4*)(out + ob + 2 * O_SZ)  = *(float4*)&r2[0];
    *(float4*)(out + ob + 2 * O_SZ + 4) = *(float4*)&r2[4];
}

extern "C" void kernel_launch(void* const* d_in, const int* in_sizes, int n_in,
                              void* d_out, int out_size, void* d_ws, size_t ws_size,
                              hipStream_t stream) {
    const float* x   = (const float*)d_in[0];
    const float* W1  = (const float*)d_in[1];
    const float* b1  = (const float*)d_in[2];
    const float* W2  = (const float*)d_in[3];
    const float* b2  = (const float*)d_in[4];
    const float* Wg  = (const float*)d_in[5];
    const float* Wgs = (const float*)d_in[6];
    float* out = (float*)d_out;

    char* ws = (char*)d_ws;
    const size_t SZ_XBF  = (size_t)B_SZ * D_SZ * 2;           // 16 MB
    const size_t SZ_W1T  = (size_t)E_SZ * H_SZ * D_SZ * 2;    // 16 MB
    const size_t SZ_W2T  = (size_t)E_SZ * O_SZ * H_SZ * 2;    // 8 MB
    const size_t SZ_EO   = (size_t)E_SZ * B_SZ * O_SZ * 2;    // 64 MB
    const size_t SZ_G    = (size_t)B_SZ * 20 * 4;             // 640 KB
    const size_t SZ_HBIG = (size_t)E_SZ * B_SZ * H_SZ * 2;    // 128 MB

    unsigned short* x_bf = (unsigned short*)ws;              ws += SZ_XBF;
    unsigned short* W1T  = (unsigned short*)ws;              ws += SZ_W1T;
    unsigned short* W2T  = (unsigned short*)ws;              ws += SZ_W2T;
    unsigned short* eo   = (unsigned short*)ws;              ws += SZ_EO;
    float* g_all         = (float*)ws;                       ws += SZ_G;
    unsigned short* h_buf = (unsigned short*)ws;

    const size_t fixed = SZ_XBF + SZ_W1T + SZ_W2T + SZ_EO + SZ_G;
    const bool big = ws_size >= fixed + SZ_HBIG;

    // 1) convert x; merged weight transposes; MFMA gates
    k_convert<<<(B_SZ * D_SZ / 8 + 255) / 256, 256, 0, stream>>>(x, x_bf, B_SZ * D_SZ / 8);
    k_transpose_both<<<dim3(16, 16, 16), dim3(64, 8), 0, stream>>>(W1, W1T, W2, W2T);
    k_gates_mfma<<<B_SZ / 32, 256, 0, stream>>>(x_bf, Wg, Wgs, g_all);

    // 2) expert GEMMs (256x256 tiles; flat 1D grids, all % 8 == 0)
    if (big) {
        k_gemm_pipe<<<(H_SZ / 256) * (B_SZ / 256) * E_SZ, 512, 0, stream>>>(
            x_bf, W1T, b1, h_buf, B_SZ, H_SZ, D_SZ,
            0LL, (long long)H_SZ * D_SZ, (long long)H_SZ, (long long)B_SZ * H_SZ, 0);
        k_gemm_pipe<<<(O_SZ / 256) * (B_SZ / 256) * E_SZ, 512, 0, stream>>>(
            h_buf, W2T, b2, eo, B_SZ, O_SZ, H_SZ,
            (long long)B_SZ * H_SZ, (long long)O_SZ * H_SZ, (long long)O_SZ, (long long)B_SZ * O_SZ, 0);
    } else {
        for (int e = 0; e < E_SZ; ++e) {
            k_gemm_pipe<<<(H_SZ / 256) * (B_SZ / 256), 512, 0, stream>>>(
                x_bf, W1T, b1, h_buf, B_SZ, H_SZ, D_SZ,
                0LL, (long long)H_SZ * D_SZ, (long long)H_SZ, 0LL, e);
            k_gemm_pipe<<<(O_SZ / 256) * (B_SZ / 256), 512, 0, stream>>>(
                h_buf, W2T, b2, eo, B_SZ, O_SZ, H_SZ,
                0LL, (long long)O_SZ * H_SZ, (long long)O_SZ, (long long)B_SZ * O_SZ, e);
        }
    }

    // 3) combine
    k_combine<<<(B_SZ * O_SZ / 8) / 256, 256, 0, stream>>>(eo, g_all, out);
}

// Round 14
// 300.915 us; speedup vs baseline: 1.0865x; 1.0074x over previous
//
#include <hip/hip_runtime.h>
#include <hip/hip_bf16.h>
#include <stdint.h>

#define B_SZ 8192
#define D_SZ 1024
#define H_SZ 1024
#define O_SZ 512
#define E_SZ 8

typedef float f32x4 __attribute__((ext_vector_type(4)));
typedef __bf16 bf16x8 __attribute__((ext_vector_type(8)));

typedef __attribute__((address_space(1))) uint32_t gu32;
typedef __attribute__((address_space(3))) uint32_t lu32;

__device__ __forceinline__ unsigned short f2bf(float f) {
    union { __hip_bfloat16 h; unsigned short u; } c;
    c.h = __float2bfloat16(f);
    return c.u;
}
__device__ __forceinline__ float bf2f(unsigned short u) {
    union { float f; uint32_t u; } c;
    c.u = ((uint32_t)u) << 16;
    return c.f;
}

// ---------------- fused prep: convert | W1 transpose | W2 transpose | gates ----------------
// Flat grid of 5248 blocks x 512 threads:
//   [0,2048)      convert x f32 -> bf16 (8 elems/thread)
//   [2048,4096)   W1 [E][1024][1024] -> W1T [E][1024][1024] transposed bf16
//   [4096,5120)   W2 [E][1024][512]  -> W2T [E][512][1024]  transposed bf16
//   [5120,5248)   gates: logits = bf16(x) @ WgAll^T via MFMA, 64 rows/block + 3 softmaxes
// Shared-mem union: 72 KiB (transpose tile 16.6K | gates wlds 66K + logits 6K).
__global__ __launch_bounds__(512) void k_prep(const float* __restrict__ x,
                                              const float* __restrict__ W1,
                                              const float* __restrict__ W2,
                                              const float* __restrict__ Wg,
                                              const float* __restrict__ Wgs,
                                              unsigned short* __restrict__ x_bf,
                                              unsigned short* __restrict__ W1T,
                                              unsigned short* __restrict__ W2T,
                                              float* __restrict__ g_all) {
    __shared__ __align__(16) char smem[72192];
    const int blk = blockIdx.x;
    const int tid = threadIdx.x;

    if (blk < 2048) {
        // ---------------- convert ----------------
        const int i = blk * 512 + tid;                 // over B*D/8 = 1048576
        const float4* p = (const float4*)x + (size_t)i * 2;
        float4 a = p[0], b = p[1];
        ushort4 lo, hi;
        lo.x = f2bf(a.x); lo.y = f2bf(a.y); lo.z = f2bf(a.z); lo.w = f2bf(a.w);
        hi.x = f2bf(b.x); hi.y = f2bf(b.y); hi.z = f2bf(b.z); hi.w = f2bf(b.w);
        ushort4* q = (ushort4*)x_bf + (size_t)i * 2;
        q[0] = lo; q[1] = hi;
        return;
    }

    if (blk < 5120) {
        // ---------------- transpose+convert (W1 or W2) ----------------
        const float* in; unsigned short* outp; int R, C, e, rem;
        if (blk < 4096) {
            const int local = blk - 2048;              // 256 blocks/expert
            in = W1; outp = W1T; R = D_SZ; C = H_SZ;
            e = local >> 8; rem = local & 255;
        } else {
            const int local = blk - 4096;              // 128 blocks/expert
            in = W2; outp = W2T; R = H_SZ; C = O_SZ;
            e = local >> 7; rem = local & 127;
        }
        const int ncx = C >> 6;
        const int c0 = (rem % ncx) * 64, r0 = (rem / ncx) * 64;
        float (*tile)[65] = (float(*)[65])smem;        // 64x65 f32 = 16.6 KiB
        const float* src = in + (size_t)e * R * C;
        unsigned short* dst = outp + (size_t)e * R * C;
        const int tx = tid & 63, ty = tid >> 6;        // (64,8)
#pragma unroll
        for (int rr = ty; rr < 64; rr += 8)
            tile[rr][tx] = src[(size_t)(r0 + rr) * C + c0 + tx];
        __syncthreads();
#pragma unroll
        for (int rr = ty; rr < 64; rr += 8)
            dst[(size_t)(c0 + rr) * R + r0 + tx] = f2bf(tile[tx][rr]);
        return;
    }

    // ---------------- gates via MFMA (reads f32 x, converts in-register) ----------------
    {
        const int bl = blk - 5120;                     // 128 blocks, 64 rows each
        unsigned short* wlds = (unsigned short*)smem;  // [32][1032] bf16 = 66048 B
        float (*logits)[24] = (float(*)[24])(smem + 66048);   // 6144 B

        // stage WgT (j-major), zero-pad j = 20..31
        for (int idx = tid; idx < 32 * 1024; idx += 512) {
            const int j = idx >> 10, k = idx & 1023;
            float v = 0.f;
            if (j < 6)       v = Wg[(size_t)k * 6 + j];
            else if (j < 12) v = Wg[(size_t)D_SZ * 6 + (size_t)k * 6 + (j - 6)];
            else if (j < 20) v = Wgs[(size_t)k * 8 + (j - 12)];
            wlds[j * 1032 + k] = f2bf(v);
        }
        __syncthreads();

        const int lane = tid & 63, w = tid >> 6;       // 8 waves
        const int rt = w >> 1, jt = w & 1;             // 4 row-tiles x 2 j-tiles
        const int lr = lane & 15, lg = lane >> 4;
        const int row0 = bl * 64 + rt * 16;

        const float* xr = x + (size_t)(row0 + lr) * D_SZ;
        const unsigned short* wrow = &wlds[(jt * 16 + lr) * 1032];

        f32x4 acc = f32x4{0.f, 0.f, 0.f, 0.f};
#pragma unroll 4
        for (int kt = 0; kt < 32; ++kt) {
            float4 a0 = *(const float4*)(xr + kt * 32 + lg * 8);
            float4 a1 = *(const float4*)(xr + kt * 32 + lg * 8 + 4);
            union { unsigned short us[8]; bf16x8 v; } fa;
            fa.us[0] = f2bf(a0.x); fa.us[1] = f2bf(a0.y);
            fa.us[2] = f2bf(a0.z); fa.us[3] = f2bf(a0.w);
            fa.us[4] = f2bf(a1.x); fa.us[5] = f2bf(a1.y);
            fa.us[6] = f2bf(a1.z); fa.us[7] = f2bf(a1.w);
            bf16x8 fb = *(const bf16x8*)(wrow + kt * 32 + lg * 8);
            acc = __builtin_amdgcn_mfma_f32_16x16x32_bf16(fa.v, fb, acc, 0, 0, 0);
        }
        const int j = jt * 16 + lr;
        if (j < 24) {
#pragma unroll
            for (int r = 0; r < 4; ++r)
                logits[rt * 16 + lg * 4 + r][j] = acc[r];
        }
        __syncthreads();

        if (tid < 64) {
            const int row = tid;
            float* g = g_all + (size_t)(bl * 64 + row) * 20;
#pragma unroll
            for (int t = 0; t < 3; ++t) {
                const int base = (t == 0) ? 0 : (t == 1 ? 6 : 12);
                const int cnt  = (t == 2) ? 8 : 6;
                float m = -1e30f;
                for (int q = 0; q < cnt; ++q) m = fmaxf(m, logits[row][base + q]);
                float ex[8]; float sum = 0.f;
                for (int q = 0; q < cnt; ++q) { ex[q] = __expf(logits[row][base + q] - m); sum += ex[q]; }
                float inv = 1.f / sum;
                for (int q = 0; q < cnt; ++q) g[base + q] = ex[q] * inv;
            }
        }
    }
}

// ------- 256x256 bf16 GEMM: ring-4 BK=32 + one-phase-ahead fragment pipeline -------
// (round-9/12/13 verified fastest: G1 = 147.5 us, 931 TF). Only change vs r13:
// #pragma unroll 2 on the main loop so (t&3) buffer bases fold to constants.
__global__ __launch_bounds__(512, 2) void k_gemm_pipe(
    const unsigned short* __restrict__ A,
    const unsigned short* __restrict__ Bt,
    const float* __restrict__ bias,
    unsigned short* __restrict__ C,
    int M, int N, int K,
    long long sA, long long sB, long long sBias, long long sC, int e_base) {

    const int tid = threadIdx.x;
    const int lane = tid & 63, wid = tid >> 6;
    const int wr = wid >> 2, wc = wid & 3;       // 2 x 4 wave grid
    const int lr = lane & 15, lg = lane >> 4;

    const int nwg = gridDim.x;
    const int wg = blockIdx.x;
    const int swz = (wg & 7) * (nwg >> 3) + (wg >> 3);
    const int nx = N >> 8;
    const int my = M >> 8;
    const int bx = swz % nx;
    const int t1 = swz / nx;
    const int by = t1 % my;
    const int e  = t1 / my + e_base;

    A    += (size_t)((long long)e * sA);
    Bt   += (size_t)((long long)e * sB);
    bias += (size_t)((long long)e * sBias);
    C    += (size_t)((long long)e * sC);

    const int m0 = by * 256, n0 = bx * 256;

    __shared__ __align__(16) unsigned short lds[65536];   // 128 KiB
    char* ldsb = (char*)lds;

    const int srow = tid >> 2;
    const int scol = (((tid & 3) ^ ((tid >> 3) & 3)) * 8);
    const int sdst = tid * 16;

    auto stageA2 = [&](int t) {
        const int bb = (t & 3) * 32768;
        const unsigned short* s0 = A + (size_t)(m0 + srow) * K + (t << 5) + scol;
        __builtin_amdgcn_global_load_lds((gu32*)s0, (lu32*)(ldsb + bb + sdst), 16, 0, 0);
        __builtin_amdgcn_global_load_lds((gu32*)(s0 + (size_t)128 * K),
                                         (lu32*)(ldsb + bb + 8192 + sdst), 16, 0, 0);
    };
    auto stageB2 = [&](int t) {
        const int bb = (t & 3) * 32768 + 16384;
        const unsigned short* s0 = Bt + (size_t)(n0 + srow) * K + (t << 5) + scol;
        __builtin_amdgcn_global_load_lds((gu32*)s0, (lu32*)(ldsb + bb + sdst), 16, 0, 0);
        __builtin_amdgcn_global_load_lds((gu32*)(s0 + (size_t)128 * K),
                                         (lu32*)(ldsb + bb + 8192 + sdst), 16, 0, 0);
    };

    const int cblk = (lg ^ ((lr >> 1) & 3)) * 16;
    const int aoff = wr * 8192 + lr * 64 + cblk;
    const int boff = 16384 + (wc >> 1) * 8192 + (wc & 1) * 4096 + lr * 64 + cblk;

    f32x4 acc[8][4];
#pragma unroll
    for (int i = 0; i < 8; ++i)
#pragma unroll
        for (int j = 0; j < 4; ++j)
            acc[i][j] = f32x4{0.f, 0.f, 0.f, 0.f};

    auto mfma16 = [&](const bf16x8 (&fa)[4], const bf16x8 (&fb)[4], int rbase) {
        __builtin_amdgcn_s_setprio(1);
#pragma unroll
        for (int i = 0; i < 4; ++i)
#pragma unroll
            for (int j = 0; j < 4; ++j)
                acc[rbase + i][j] = __builtin_amdgcn_mfma_f32_16x16x32_bf16(
                    fa[i], fb[j], acc[rbase + i][j], 0, 0, 0);
        __builtin_amdgcn_s_setprio(0);
    };

    const int NT = K >> 5;   // 32 (divisible by 4)

    stageA2(0); stageB2(0); stageA2(1); stageB2(1); stageA2(2); stageB2(2);
    asm volatile("s_waitcnt vmcnt(8)" ::: "memory");
    asm volatile("s_barrier" ::: "memory");

    bf16x8 aU0[4], aL0[4], b0[4], aU1[4], aL1[4], b1v[4];
#pragma unroll
    for (int i = 0; i < 4; ++i) aU0[i] = *(const bf16x8*)(ldsb + aoff + i * 1024);
#pragma unroll
    for (int j = 0; j < 4; ++j) b0[j]  = *(const bf16x8*)(ldsb + boff + j * 1024);

#pragma unroll 2
    for (int t = 0; t < NT; t += 2) {
        const int bb0 = (t & 3) * 32768;
        const int bb1 = ((t + 1) & 3) * 32768;
        const int bb2 = ((t + 2) & 3) * 32768;

        // ---- phase (t,U): read L-frags(t); ensure t+1 landed; MFMA U(t) ----
#pragma unroll
        for (int i = 0; i < 4; ++i) aL0[i] = *(const bf16x8*)(ldsb + bb0 + aoff + (4 + i) * 1024);
        if (t + 2 < NT) { asm volatile("s_waitcnt vmcnt(4)" ::: "memory"); }
        else            { asm volatile("s_waitcnt vmcnt(0)" ::: "memory"); }
        asm volatile("s_barrier" ::: "memory");
        if (t + 3 < NT) stageA2(t + 3);
        mfma16(aU0, b0, 0);

        // ---- phase (t,L): read U-frags(t+1); MFMA L(t) ----
#pragma unroll
        for (int i = 0; i < 4; ++i) aU1[i] = *(const bf16x8*)(ldsb + bb1 + aoff + i * 1024);
#pragma unroll
        for (int j = 0; j < 4; ++j) b1v[j] = *(const bf16x8*)(ldsb + bb1 + boff + j * 1024);
        asm volatile("s_barrier" ::: "memory");
        if (t + 3 < NT) stageB2(t + 3);
        mfma16(aL0, b0, 4);

        // ---- phase (t+1,U): read L-frags(t+1); ensure t+2 landed; MFMA U(t+1) ----
#pragma unroll
        for (int i = 0; i < 4; ++i) aL1[i] = *(const bf16x8*)(ldsb + bb1 + aoff + (4 + i) * 1024);
        if (t + 3 < NT) { asm volatile("s_waitcnt vmcnt(4)" ::: "memory"); }
        else            { asm volatile("s_waitcnt vmcnt(0)" ::: "memory"); }
        asm volatile("s_barrier" ::: "memory");
        if (t + 4 < NT) stageA2(t + 4);
        mfma16(aU1, b1v, 0);

        // ---- phase (t+1,L): read U-frags(t+2); MFMA L(t+1) ----
        if (t + 2 < NT) {
#pragma unroll
            for (int i = 0; i < 4; ++i) aU0[i] = *(const bf16x8*)(ldsb + bb2 + aoff + i * 1024);
#pragma unroll
            for (int j = 0; j < 4; ++j) b0[j]  = *(const bf16x8*)(ldsb + bb2 + boff + j * 1024);
        }
        asm volatile("s_barrier" ::: "memory");
        if (t + 4 < NT) stageB2(t + 4);
        mfma16(aL1, b1v, 4);
    }

    __syncthreads();
    unsigned short* ct = (unsigned short*)ldsb;
#pragma unroll
    for (int j = 0; j < 4; ++j) {
        const int nn = wc * 64 + j * 16 + lr;
        const float bv = bias[n0 + nn];
#pragma unroll
        for (int i = 0; i < 8; ++i) {
            const int mb = wr * 128 + i * 16 + lg * 4;
#pragma unroll
            for (int r = 0; r < 4; ++r) {
                float v = fmaxf(acc[i][j][r] + bv, 0.f);
                ct[(size_t)(mb + r) * 256 + nn] = f2bf(v);
            }
        }
    }
    __syncthreads();
#pragma unroll
    for (int it = 0; it < 16; ++it) {
        const int row = it * 16 + (tid >> 5);
        const int colE = (tid & 31) * 8;
        *(int4*)(&C[(size_t)(m0 + row) * N + n0 + colE]) =
            *(const int4*)(ldsb + it * 8192 + (size_t)tid * 16);
    }
}

// ---------------- combine: out[b][t][o], 8 o's per thread ----------------
__global__ __launch_bounds__(256) void k_combine(const unsigned short* __restrict__ eo,
                                                 const float* __restrict__ g_all,
                                                 float* __restrict__ out) {
    int idx8 = blockIdx.x * 256 + threadIdx.x;    // over B*O/8
    int b = idx8 >> 6;                            // O/8 = 64
    int o8 = (idx8 & 63) * 8;
    const float* g = g_all + (size_t)b * 20;
    float v[E_SZ][8];
#pragma unroll
    for (int e = 0; e < E_SZ; ++e) {
        const unsigned short* p = eo + (size_t)e * B_SZ * O_SZ + (size_t)b * O_SZ + o8;
        int4 u = *(const int4*)p;
        const unsigned short* us = (const unsigned short*)&u;
#pragma unroll
        for (int c = 0; c < 8; ++c) v[e][c] = bf2f(us[c]);
    }
    float r0[8], r1[8], r2[8];
#pragma unroll
    for (int c = 0; c < 8; ++c) {
        r0[c] = g[0] * v[0][c] + g[1] * v[1][c] + g[2] * v[4][c] + g[3] * v[5][c]
              + g[4] * v[6][c] + g[5] * v[7][c];
        r1[c] = g[6] * v[2][c] + g[7] * v[3][c] + g[8] * v[4][c] + g[9] * v[5][c]
              + g[10] * v[6][c] + g[11] * v[7][c];
        float s = 0.f;
#pragma unroll
        for (int e = 0; e < E_SZ; ++e) s += g[12 + e] * v[e][c];
        r2[c] = s;
    }
    size_t ob = (size_t)b * (3 * O_SZ) + o8;
    *(float4*)(out + ob)             = *(float4*)&r0[0];
    *(float4*)(out + ob + 4)         = *(float4*)&r0[4];
    *(float4*)(out + ob + O_SZ)      = *(float4*)&r1[0];
    *(float4*)(out + ob + O_SZ + 4)  = *(float4*)&r1[4];
    *(float4*)(out + ob + 2 * O_SZ)  = *(float4*)&r2[0];
    *(float4*)(out + ob + 2 * O_SZ + 4) = *(float4*)&r2[4];
}

extern "C" void kernel_launch(void* const* d_in, const int* in_sizes, int n_in,
                              void* d_out, int out_size, void* d_ws, size_t ws_size,
                              hipStream_t stream) {
    const float* x   = (const float*)d_in[0];
    const float* W1  = (const float*)d_in[1];
    const float* b1  = (const float*)d_in[2];
    const float* W2  = (const float*)d_in[3];
    const float* b2  = (const float*)d_in[4];
    const float* Wg  = (const float*)d_in[5];
    const float* Wgs = (const float*)d_in[6];
    float* out = (float*)d_out;

    char* ws = (char*)d_ws;
    const size_t SZ_XBF  = (size_t)B_SZ * D_SZ * 2;           // 16 MB
    const size_t SZ_W1T  = (size_t)E_SZ * H_SZ * D_SZ * 2;    // 16 MB
    const size_t SZ_W2T  = (size_t)E_SZ * O_SZ * H_SZ * 2;    // 8 MB
    const size_t SZ_EO   = (size_t)E_SZ * B_SZ * O_SZ * 2;    // 64 MB
    const size_t SZ_G    = (size_t)B_SZ * 20 * 4;             // 640 KB
    const size_t SZ_HBIG = (size_t)E_SZ * B_SZ * H_SZ * 2;    // 128 MB

    unsigned short* x_bf = (unsigned short*)ws;              ws += SZ_XBF;
    unsigned short* W1T  = (unsigned short*)ws;              ws += SZ_W1T;
    unsigned short* W2T  = (unsigned short*)ws;              ws += SZ_W2T;
    unsigned short* eo   = (unsigned short*)ws;              ws += SZ_EO;
    float* g_all         = (float*)ws;                       ws += SZ_G;
    unsigned short* h_buf = (unsigned short*)ws;

    const size_t fixed = SZ_XBF + SZ_W1T + SZ_W2T + SZ_EO + SZ_G;
    const bool big = ws_size >= fixed + SZ_HBIG;

    // 1) fused prep: convert | transposes | gates  (one launch)
    k_prep<<<5248, 512, 0, stream>>>(x, W1, W2, Wg, Wgs, x_bf, W1T, W2T, g_all);

    // 2) expert GEMMs (256x256 tiles; flat 1D grids, all % 8 == 0)
    if (big) {
        k_gemm_pipe<<<(H_SZ / 256) * (B_SZ / 256) * E_SZ, 512, 0, stream>>>(
            x_bf, W1T, b1, h_buf, B_SZ, H_SZ, D_SZ,
            0LL, (long long)H_SZ * D_SZ, (long long)H_SZ, (long long)B_SZ * H_SZ, 0);
        k_gemm_pipe<<<(O_SZ / 256) * (B_SZ / 256) * E_SZ, 512, 0, stream>>>(
            h_buf, W2T, b2, eo, B_SZ, O_SZ, H_SZ,
            (long long)B_SZ * H_SZ, (long long)O_SZ * H_SZ, (long long)O_SZ, (long long)B_SZ * O_SZ, 0);
    } else {
        for (int e = 0; e < E_SZ; ++e) {
            k_gemm_pipe<<<(H_SZ / 256) * (B_SZ / 256), 512, 0, stream>>>(
                x_bf, W1T, b1, h_buf, B_SZ, H_SZ, D_SZ,
                0LL, (long long)H_SZ * D_SZ, (long long)H_SZ, 0LL, e);
            k_gemm_pipe<<<(O_SZ / 256) * (B_SZ / 256), 512, 0, stream>>>(
                h_buf, W2T, b2, eo, B_SZ, O_SZ, H_SZ,
                0LL, (long long)O_SZ * H_SZ, (long long)O_SZ, (long long)B_SZ * O_SZ, e);
        }
    }

    // 3) combine
    k_combine<<<(B_SZ * O_SZ / 8) / 256, 256, 0, stream>>>(eo, g_all, out);
}

// Round 15
// 297.518 us; speedup vs baseline: 1.0989x; 1.0114x over previous
//
#include <hip/hip_runtime.h>
#include <hip/hip_bf16.h>
#include <stdint.h>

#define B_SZ 8192
#define D_SZ 1024
#define H_SZ 1024
#define O_SZ 512
#define E_SZ 8

typedef float f32x4 __attribute__((ext_vector_type(4)));
typedef __bf16 bf16x8 __attribute__((ext_vector_type(8)));

typedef __attribute__((address_space(1))) uint32_t gu32;
typedef __attribute__((address_space(3))) uint32_t lu32;

__device__ __forceinline__ unsigned short f2bf(float f) {
    union { __hip_bfloat16 h; unsigned short u; } c;
    c.h = __float2bfloat16(f);
    return c.u;
}
__device__ __forceinline__ float bf2f(unsigned short u) {
    union { float f; uint32_t u; } c;
    c.u = ((uint32_t)u) << 16;
    return c.f;
}

// ---------------- fused prep: convert | W1 transpose | W2 transpose | gates ----------------
__global__ __launch_bounds__(512) void k_prep(const float* __restrict__ x,
                                              const float* __restrict__ W1,
                                              const float* __restrict__ W2,
                                              const float* __restrict__ Wg,
                                              const float* __restrict__ Wgs,
                                              unsigned short* __restrict__ x_bf,
                                              unsigned short* __restrict__ W1T,
                                              unsigned short* __restrict__ W2T,
                                              float* __restrict__ g_all) {
    __shared__ __align__(16) char smem[72192];
    const int blk = blockIdx.x;
    const int tid = threadIdx.x;

    if (blk < 2048) {
        const int i = blk * 512 + tid;
        const float4* p = (const float4*)x + (size_t)i * 2;
        float4 a = p[0], b = p[1];
        ushort4 lo, hi;
        lo.x = f2bf(a.x); lo.y = f2bf(a.y); lo.z = f2bf(a.z); lo.w = f2bf(a.w);
        hi.x = f2bf(b.x); hi.y = f2bf(b.y); hi.z = f2bf(b.z); hi.w = f2bf(b.w);
        ushort4* q = (ushort4*)x_bf + (size_t)i * 2;
        q[0] = lo; q[1] = hi;
        return;
    }

    if (blk < 5120) {
        const float* in; unsigned short* outp; int R, C, e, rem;
        if (blk < 4096) {
            const int local = blk - 2048;
            in = W1; outp = W1T; R = D_SZ; C = H_SZ;
            e = local >> 8; rem = local & 255;
        } else {
            const int local = blk - 4096;
            in = W2; outp = W2T; R = H_SZ; C = O_SZ;
            e = local >> 7; rem = local & 127;
        }
        const int ncx = C >> 6;
        const int c0 = (rem % ncx) * 64, r0 = (rem / ncx) * 64;
        float (*tile)[65] = (float(*)[65])smem;
        const float* src = in + (size_t)e * R * C;
        unsigned short* dst = outp + (size_t)e * R * C;
        const int tx = tid & 63, ty = tid >> 6;
#pragma unroll
        for (int rr = ty; rr < 64; rr += 8)
            tile[rr][tx] = src[(size_t)(r0 + rr) * C + c0 + tx];
        __syncthreads();
#pragma unroll
        for (int rr = ty; rr < 64; rr += 8)
            dst[(size_t)(c0 + rr) * R + r0 + tx] = f2bf(tile[tx][rr]);
        return;
    }

    {
        const int bl = blk - 5120;
        unsigned short* wlds = (unsigned short*)smem;
        float (*logits)[24] = (float(*)[24])(smem + 66048);

        for (int idx = tid; idx < 32 * 1024; idx += 512) {
            const int j = idx >> 10, k = idx & 1023;
            float v = 0.f;
            if (j < 6)       v = Wg[(size_t)k * 6 + j];
            else if (j < 12) v = Wg[(size_t)D_SZ * 6 + (size_t)k * 6 + (j - 6)];
            else if (j < 20) v = Wgs[(size_t)k * 8 + (j - 12)];
            wlds[j * 1032 + k] = f2bf(v);
        }
        __syncthreads();

        const int lane = tid & 63, w = tid >> 6;
        const int rt = w >> 1, jt = w & 1;
        const int lr = lane & 15, lg = lane >> 4;
        const int row0 = bl * 64 + rt * 16;

        const float* xr = x + (size_t)(row0 + lr) * D_SZ;
        const unsigned short* wrow = &wlds[(jt * 16 + lr) * 1032];

        f32x4 acc = f32x4{0.f, 0.f, 0.f, 0.f};
#pragma unroll 4
        for (int kt = 0; kt < 32; ++kt) {
            float4 a0 = *(const float4*)(xr + kt * 32 + lg * 8);
            float4 a1 = *(const float4*)(xr + kt * 32 + lg * 8 + 4);
            union { unsigned short us[8]; bf16x8 v; } fa;
            fa.us[0] = f2bf(a0.x); fa.us[1] = f2bf(a0.y);
            fa.us[2] = f2bf(a0.z); fa.us[3] = f2bf(a0.w);
            fa.us[4] = f2bf(a1.x); fa.us[5] = f2bf(a1.y);
            fa.us[6] = f2bf(a1.z); fa.us[7] = f2bf(a1.w);
            bf16x8 fb = *(const bf16x8*)(wrow + kt * 32 + lg * 8);
            acc = __builtin_amdgcn_mfma_f32_16x16x32_bf16(fa.v, fb, acc, 0, 0, 0);
        }
        const int j = jt * 16 + lr;
        if (j < 24) {
#pragma unroll
            for (int r = 0; r < 4; ++r)
                logits[rt * 16 + lg * 4 + r][j] = acc[r];
        }
        __syncthreads();

        if (tid < 64) {
            const int row = tid;
            float* g = g_all + (size_t)(bl * 64 + row) * 20;
#pragma unroll
            for (int t = 0; t < 3; ++t) {
                const int base = (t == 0) ? 0 : (t == 1 ? 6 : 12);
                const int cnt  = (t == 2) ? 8 : 6;
                float m = -1e30f;
                for (int q = 0; q < cnt; ++q) m = fmaxf(m, logits[row][base + q]);
                float ex[8]; float sum = 0.f;
                for (int q = 0; q < cnt; ++q) { ex[q] = __expf(logits[row][base + q] - m); sum += ex[q]; }
                float inv = 1.f / sum;
                for (int q = 0; q < cnt; ++q) g[base + q] = ex[q] * inv;
            }
        }
    }
}

// ------- 256x256 bf16 GEMM: ring-4 BK=32, one-phase-ahead reads, DEPTH-6 counted vmcnt -------
// Change vs r14 (which matched r9's 147.5 us): stage issuance moved BEFORE the wait,
// wait deepened vmcnt(4) -> vmcnt(6) (m201's in-flight depth).
// Safety (m135 oldest-first vmcnt semantics):
//  phase (t,U): after issuing stageA2(t+3), outstanding = t+2's 4 + t+3A's 2 = 6
//    -> vmcnt(6) guarantees ALL of t+1 landed; barrier globalizes; (t,L) reads t+1. RAW ok.
//  phase (t+1,U): after stageA2(t+4), outstanding = t+3's 4 + t+4A's 2 = 6
//    -> vmcnt(6) guarantees t+2 landed; (t+1,L) reads t+2. RAW ok.
//  WAR: ring-4 stage target (t+3)&3 / (t+4)&3 never aliases readable {t,t+1,t+2}.
//  Tails: no-stage -> vmcnt(4) (only prior tile's 4 outstanding); last -> vmcnt(0).
__global__ __launch_bounds__(512, 2) void k_gemm_pipe(
    const unsigned short* __restrict__ A,
    const unsigned short* __restrict__ Bt,
    const float* __restrict__ bias,
    unsigned short* __restrict__ C,
    int M, int N, int K,
    long long sA, long long sB, long long sBias, long long sC, int e_base) {

    const int tid = threadIdx.x;
    const int lane = tid & 63, wid = tid >> 6;
    const int wr = wid >> 2, wc = wid & 3;       // 2 x 4 wave grid
    const int lr = lane & 15, lg = lane >> 4;

    const int nwg = gridDim.x;
    const int wg = blockIdx.x;
    const int swz = (wg & 7) * (nwg >> 3) + (wg >> 3);
    const int nx = N >> 8;
    const int my = M >> 8;
    const int bx = swz % nx;
    const int t1 = swz / nx;
    const int by = t1 % my;
    const int e  = t1 / my + e_base;

    A    += (size_t)((long long)e * sA);
    Bt   += (size_t)((long long)e * sB);
    bias += (size_t)((long long)e * sBias);
    C    += (size_t)((long long)e * sC);

    const int m0 = by * 256, n0 = bx * 256;

    __shared__ __align__(16) unsigned short lds[65536];   // 128 KiB
    char* ldsb = (char*)lds;

    const int srow = tid >> 2;
    const int scol = (((tid & 3) ^ ((tid >> 3) & 3)) * 8);
    const int sdst = tid * 16;

    auto stageA2 = [&](int t) {
        const int bb = (t & 3) * 32768;
        const unsigned short* s0 = A + (size_t)(m0 + srow) * K + (t << 5) + scol;
        __builtin_amdgcn_global_load_lds((gu32*)s0, (lu32*)(ldsb + bb + sdst), 16, 0, 0);
        __builtin_amdgcn_global_load_lds((gu32*)(s0 + (size_t)128 * K),
                                         (lu32*)(ldsb + bb + 8192 + sdst), 16, 0, 0);
    };
    auto stageB2 = [&](int t) {
        const int bb = (t & 3) * 32768 + 16384;
        const unsigned short* s0 = Bt + (size_t)(n0 + srow) * K + (t << 5) + scol;
        __builtin_amdgcn_global_load_lds((gu32*)s0, (lu32*)(ldsb + bb + sdst), 16, 0, 0);
        __builtin_amdgcn_global_load_lds((gu32*)(s0 + (size_t)128 * K),
                                         (lu32*)(ldsb + bb + 8192 + sdst), 16, 0, 0);
    };

    const int cblk = (lg ^ ((lr >> 1) & 3)) * 16;
    const int aoff = wr * 8192 + lr * 64 + cblk;
    const int boff = 16384 + (wc >> 1) * 8192 + (wc & 1) * 4096 + lr * 64 + cblk;

    f32x4 acc[8][4];
#pragma unroll
    for (int i = 0; i < 8; ++i)
#pragma unroll
        for (int j = 0; j < 4; ++j)
            acc[i][j] = f32x4{0.f, 0.f, 0.f, 0.f};

    auto mfma16 = [&](const bf16x8 (&fa)[4], const bf16x8 (&fb)[4], int rbase) {
        __builtin_amdgcn_s_setprio(1);
#pragma unroll
        for (int i = 0; i < 4; ++i)
#pragma unroll
            for (int j = 0; j < 4; ++j)
                acc[rbase + i][j] = __builtin_amdgcn_mfma_f32_16x16x32_bf16(
                    fa[i], fb[j], acc[rbase + i][j], 0, 0, 0);
        __builtin_amdgcn_s_setprio(0);
    };

    const int NT = K >> 5;   // 32 (divisible by 4)

    // prologue: stage tiles 0,1,2 (12 glds); vmcnt(8) -> tile 0 landed
    stageA2(0); stageB2(0); stageA2(1); stageB2(1); stageA2(2); stageB2(2);
    asm volatile("s_waitcnt vmcnt(8)" ::: "memory");
    asm volatile("s_barrier" ::: "memory");

    bf16x8 aU0[4], aL0[4], b0[4], aU1[4], aL1[4], b1v[4];
#pragma unroll
    for (int i = 0; i < 4; ++i) aU0[i] = *(const bf16x8*)(ldsb + aoff + i * 1024);
#pragma unroll
    for (int j = 0; j < 4; ++j) b0[j]  = *(const bf16x8*)(ldsb + boff + j * 1024);

#pragma unroll 2
    for (int t = 0; t < NT; t += 2) {
        const int bb0 = (t & 3) * 32768;
        const int bb1 = ((t + 1) & 3) * 32768;
        const int bb2 = ((t + 2) & 3) * 32768;

        // ---- phase (t,U): read L-frags(t); stage A(t+3); depth-6 wait; MFMA U(t) ----
#pragma unroll
        for (int i = 0; i < 4; ++i) aL0[i] = *(const bf16x8*)(ldsb + bb0 + aoff + (4 + i) * 1024);
        if (t + 3 < NT) { stageA2(t + 3);
                          asm volatile("s_waitcnt vmcnt(6)" ::: "memory"); }
        else if (t + 2 < NT) { asm volatile("s_waitcnt vmcnt(4)" ::: "memory"); }
        else                 { asm volatile("s_waitcnt vmcnt(0)" ::: "memory"); }
        asm volatile("s_barrier" ::: "memory");
        mfma16(aU0, b0, 0);

        // ---- phase (t,L): read U-frags(t+1); stage B(t+3); MFMA L(t) ----
#pragma unroll
        for (int i = 0; i < 4; ++i) aU1[i] = *(const bf16x8*)(ldsb + bb1 + aoff + i * 1024);
#pragma unroll
        for (int j = 0; j < 4; ++j) b1v[j] = *(const bf16x8*)(ldsb + bb1 + boff + j * 1024);
        if (t + 3 < NT) stageB2(t + 3);
        asm volatile("s_barrier" ::: "memory");
        mfma16(aL0, b0, 4);

        // ---- phase (t+1,U): read L-frags(t+1); stage A(t+4); depth-6 wait; MFMA U(t+1) ----
#pragma unroll
        for (int i = 0; i < 4; ++i) aL1[i] = *(const bf16x8*)(ldsb + bb1 + aoff + (4 + i) * 1024);
        if (t + 4 < NT) { stageA2(t + 4);
                          asm volatile("s_waitcnt vmcnt(6)" ::: "memory"); }
        else if (t + 3 < NT) { asm volatile("s_waitcnt vmcnt(4)" ::: "memory"); }
        else                 { asm volatile("s_waitcnt vmcnt(0)" ::: "memory"); }
        asm volatile("s_barrier" ::: "memory");
        mfma16(aU1, b1v, 0);

        // ---- phase (t+1,L): read U-frags(t+2); stage B(t+4); MFMA L(t+1) ----
        if (t + 2 < NT) {
#pragma unroll
            for (int i = 0; i < 4; ++i) aU0[i] = *(const bf16x8*)(ldsb + bb2 + aoff + i * 1024);
#pragma unroll
            for (int j = 0; j < 4; ++j) b0[j]  = *(const bf16x8*)(ldsb + bb2 + boff + j * 1024);
        }
        if (t + 4 < NT) stageB2(t + 4);
        asm volatile("s_barrier" ::: "memory");
        mfma16(aL1, b1v, 4);
    }

    // ---- epilogue: bias + relu -> LDS tile -> coalesced dwordx4 stores ----
    __syncthreads();
    unsigned short* ct = (unsigned short*)ldsb;
#pragma unroll
    for (int j = 0; j < 4; ++j) {
        const int nn = wc * 64 + j * 16 + lr;
        const float bv = bias[n0 + nn];
#pragma unroll
        for (int i = 0; i < 8; ++i) {
            const int mb = wr * 128 + i * 16 + lg * 4;
#pragma unroll
            for (int r = 0; r < 4; ++r) {
                float v = fmaxf(acc[i][j][r] + bv, 0.f);
                ct[(size_t)(mb + r) * 256 + nn] = f2bf(v);
            }
        }
    }
    __syncthreads();
#pragma unroll
    for (int it = 0; it < 16; ++it) {
        const int row = it * 16 + (tid >> 5);
        const int colE = (tid & 31) * 8;
        *(int4*)(&C[(size_t)(m0 + row) * N + n0 + colE]) =
            *(const int4*)(ldsb + it * 8192 + (size_t)tid * 16);
    }
}

// ---------------- combine: out[b][t][o], 8 o's per thread ----------------
__global__ __launch_bounds__(256) void k_combine(const unsigned short* __restrict__ eo,
                                                 const float* __restrict__ g_all,
                                                 float* __restrict__ out) {
    int idx8 = blockIdx.x * 256 + threadIdx.x;    // over B*O/8
    int b = idx8 >> 6;                            // O/8 = 64
    int o8 = (idx8 & 63) * 8;
    const float* g = g_all + (size_t)b * 20;
    float v[E_SZ][8];
#pragma unroll
    for (int e = 0; e < E_SZ; ++e) {
        const unsigned short* p = eo + (size_t)e * B_SZ * O_SZ + (size_t)b * O_SZ + o8;
        int4 u = *(const int4*)p;
        const unsigned short* us = (const unsigned short*)&u;
#pragma unroll
        for (int c = 0; c < 8; ++c) v[e][c] = bf2f(us[c]);
    }
    float r0[8], r1[8], r2[8];
#pragma unroll
    for (int c = 0; c < 8; ++c) {
        r0[c] = g[0] * v[0][c] + g[1] * v[1][c] + g[2] * v[4][c] + g[3] * v[5][c]
              + g[4] * v[6][c] + g[5] * v[7][c];
        r1[c] = g[6] * v[2][c] + g[7] * v[3][c] + g[8] * v[4][c] + g[9] * v[5][c]
              + g[10] * v[6][c] + g[11] * v[7][c];
        float s = 0.f;
#pragma unroll
        for (int e = 0; e < E_SZ; ++e) s += g[12 + e] * v[e][c];
        r2[c] = s;
    }
    size_t ob = (size_t)b * (3 * O_SZ) + o8;
    *(float4*)(out + ob)             = *(float4*)&r0[0];
    *(float4*)(out + ob + 4)         = *(float4*)&r0[4];
    *(float4*)(out + ob + O_SZ)      = *(float4*)&r1[0];
    *(float4*)(out + ob + O_SZ + 4)  = *(float4*)&r1[4];
    *(float4*)(out + ob + 2 * O_SZ)  = *(float4*)&r2[0];
    *(float4*)(out + ob + 2 * O_SZ + 4) = *(float4*)&r2[4];
}

extern "C" void kernel_launch(void* const* d_in, const int* in_sizes, int n_in,
                              void* d_out, int out_size, void* d_ws, size_t ws_size,
                              hipStream_t stream) {
    const float* x   = (const float*)d_in[0];
    const float* W1  = (const float*)d_in[1];
    const float* b1  = (const float*)d_in[2];
    const float* W2  = (const float*)d_in[3];
    const float* b2  = (const float*)d_in[4];
    const float* Wg  = (const float*)d_in[5];
    const float* Wgs = (const float*)d_in[6];
    float* out = (float*)d_out;

    char* ws = (char*)d_ws;
    const size_t SZ_XBF  = (size_t)B_SZ * D_SZ * 2;           // 16 MB
    const size_t SZ_W1T  = (size_t)E_SZ * H_SZ * D_SZ * 2;    // 16 MB
    const size_t SZ_W2T  = (size_t)E_SZ * O_SZ * H_SZ * 2;    // 8 MB
    const size_t SZ_EO   = (size_t)E_SZ * B_SZ * O_SZ * 2;    // 64 MB
    const size_t SZ_G    = (size_t)B_SZ * 20 * 4;             // 640 KB
    const size_t SZ_HBIG = (size_t)E_SZ * B_SZ * H_SZ * 2;    // 128 MB

    unsigned short* x_bf = (unsigned short*)ws;              ws += SZ_XBF;
    unsigned short* W1T  = (unsigned short*)ws;              ws += SZ_W1T;
    unsigned short* W2T  = (unsigned short*)ws;              ws += SZ_W2T;
    unsigned short* eo   = (unsigned short*)ws;              ws += SZ_EO;
    float* g_all         = (float*)ws;                       ws += SZ_G;
    unsigned short* h_buf = (unsigned short*)ws;

    const size_t fixed = SZ_XBF + SZ_W1T + SZ_W2T + SZ_EO + SZ_G;
    const bool big = ws_size >= fixed + SZ_HBIG;

    // 1) fused prep: convert | transposes | gates  (one launch)
    k_prep<<<5248, 512, 0, stream>>>(x, W1, W2, Wg, Wgs, x_bf, W1T, W2T, g_all);

    // 2) expert GEMMs (256x256 tiles; flat 1D grids, all % 8 == 0)
    if (big) {
        k_gemm_pipe<<<(H_SZ / 256) * (B_SZ / 256) * E_SZ, 512, 0, stream>>>(
            x_bf, W1T, b1, h_buf, B_SZ, H_SZ, D_SZ,
            0LL, (long long)H_SZ * D_SZ, (long long)H_SZ, (long long)B_SZ * H_SZ, 0);
        k_gemm_pipe<<<(O_SZ / 256) * (B_SZ / 256) * E_SZ, 512, 0, stream>>>(
            h_buf, W2T, b2, eo, B_SZ, O_SZ, H_SZ,
            (long long)B_SZ * H_SZ, (long long)O_SZ * H_SZ, (long long)O_SZ, (long long)B_SZ * O_SZ, 0);
    } else {
        for (int e = 0; e < E_SZ; ++e) {
            k_gemm_pipe<<<(H_SZ / 256) * (B_SZ / 256), 512, 0, stream>>>(
                x_bf, W1T, b1, h_buf, B_SZ, H_SZ, D_SZ,
                0LL, (long long)H_SZ * D_SZ, (long long)H_SZ, 0LL, e);
            k_gemm_pipe<<<(O_SZ / 256) * (B_SZ / 256), 512, 0, stream>>>(
                h_buf, W2T, b2, eo, B_SZ, O_SZ, H_SZ,
                0LL, (long long)O_SZ * H_SZ, (long long)O_SZ, (long long)B_SZ * O_SZ, e);
        }
    }

    // 3) combine
    k_combine<<<(B_SZ * O_SZ / 8) / 256, 256, 0, stream>>>(eo, g_all, out);
}

// Round 16
// 296.405 us; speedup vs baseline: 1.1030x; 1.0038x over previous
//
#include <hip/hip_runtime.h>
#include <hip/hip_bf16.h>
#include <stdint.h>

#define B_SZ 8192
#define D_SZ 1024
#define H_SZ 1024
#define O_SZ 512
#define E_SZ 8

typedef float f32x4 __attribute__((ext_vector_type(4)));
typedef __bf16 bf16x8 __attribute__((ext_vector_type(8)));

typedef __attribute__((address_space(1))) uint32_t gu32;
typedef __attribute__((address_space(3))) uint32_t lu32;

__device__ __forceinline__ unsigned short f2bf(float f) {
    union { __hip_bfloat16 h; unsigned short u; } c;
    c.h = __float2bfloat16(f);
    return c.u;
}
__device__ __forceinline__ float bf2f(unsigned short u) {
    union { float f; uint32_t u; } c;
    c.u = ((uint32_t)u) << 16;
    return c.f;
}

// ---------------- fused prep: convert | W1 transpose | W2 transpose | gates ----------------
__global__ __launch_bounds__(512) void k_prep(const float* __restrict__ x,
                                              const float* __restrict__ W1,
                                              const float* __restrict__ W2,
                                              const float* __restrict__ Wg,
                                              const float* __restrict__ Wgs,
                                              unsigned short* __restrict__ x_bf,
                                              unsigned short* __restrict__ W1T,
                                              unsigned short* __restrict__ W2T,
                                              float* __restrict__ g_all) {
    __shared__ __align__(16) char smem[72192];
    const int blk = blockIdx.x;
    const int tid = threadIdx.x;

    if (blk < 2048) {
        const int i = blk * 512 + tid;
        const float4* p = (const float4*)x + (size_t)i * 2;
        float4 a = p[0], b = p[1];
        ushort4 lo, hi;
        lo.x = f2bf(a.x); lo.y = f2bf(a.y); lo.z = f2bf(a.z); lo.w = f2bf(a.w);
        hi.x = f2bf(b.x); hi.y = f2bf(b.y); hi.z = f2bf(b.z); hi.w = f2bf(b.w);
        ushort4* q = (ushort4*)x_bf + (size_t)i * 2;
        q[0] = lo; q[1] = hi;
        return;
    }

    if (blk < 5120) {
        const float* in; unsigned short* outp; int R, C, e, rem;
        if (blk < 4096) {
            const int local = blk - 2048;
            in = W1; outp = W1T; R = D_SZ; C = H_SZ;
            e = local >> 8; rem = local & 255;
        } else {
            const int local = blk - 4096;
            in = W2; outp = W2T; R = H_SZ; C = O_SZ;
            e = local >> 7; rem = local & 127;
        }
        const int ncx = C >> 6;
        const int c0 = (rem % ncx) * 64, r0 = (rem / ncx) * 64;
        float (*tile)[65] = (float(*)[65])smem;
        const float* src = in + (size_t)e * R * C;
        unsigned short* dst = outp + (size_t)e * R * C;
        const int tx = tid & 63, ty = tid >> 6;
#pragma unroll
        for (int rr = ty; rr < 64; rr += 8)
            tile[rr][tx] = src[(size_t)(r0 + rr) * C + c0 + tx];
        __syncthreads();
#pragma unroll
        for (int rr = ty; rr < 64; rr += 8)
            dst[(size_t)(c0 + rr) * R + r0 + tx] = f2bf(tile[tx][rr]);
        return;
    }

    {
        const int bl = blk - 5120;
        unsigned short* wlds = (unsigned short*)smem;
        float (*logits)[24] = (float(*)[24])(smem + 66048);

        for (int idx = tid; idx < 32 * 1024; idx += 512) {
            const int j = idx >> 10, k = idx & 1023;
            float v = 0.f;
            if (j < 6)       v = Wg[(size_t)k * 6 + j];
            else if (j < 12) v = Wg[(size_t)D_SZ * 6 + (size_t)k * 6 + (j - 6)];
            else if (j < 20) v = Wgs[(size_t)k * 8 + (j - 12)];
            wlds[j * 1032 + k] = f2bf(v);
        }
        __syncthreads();

        const int lane = tid & 63, w = tid >> 6;
        const int rt = w >> 1, jt = w & 1;
        const int lr = lane & 15, lg = lane >> 4;
        const int row0 = bl * 64 + rt * 16;

        const float* xr = x + (size_t)(row0 + lr) * D_SZ;
        const unsigned short* wrow = &wlds[(jt * 16 + lr) * 1032];

        f32x4 acc = f32x4{0.f, 0.f, 0.f, 0.f};
#pragma unroll 4
        for (int kt = 0; kt < 32; ++kt) {
            float4 a0 = *(const float4*)(xr + kt * 32 + lg * 8);
            float4 a1 = *(const float4*)(xr + kt * 32 + lg * 8 + 4);
            union { unsigned short us[8]; bf16x8 v; } fa;
            fa.us[0] = f2bf(a0.x); fa.us[1] = f2bf(a0.y);
            fa.us[2] = f2bf(a0.z); fa.us[3] = f2bf(a0.w);
            fa.us[4] = f2bf(a1.x); fa.us[5] = f2bf(a1.y);
            fa.us[6] = f2bf(a1.z); fa.us[7] = f2bf(a1.w);
            bf16x8 fb = *(const bf16x8*)(wrow + kt * 32 + lg * 8);
            acc = __builtin_amdgcn_mfma_f32_16x16x32_bf16(fa.v, fb, acc, 0, 0, 0);
        }
        const int j = jt * 16 + lr;
        if (j < 24) {
#pragma unroll
            for (int r = 0; r < 4; ++r)
                logits[rt * 16 + lg * 4 + r][j] = acc[r];
        }
        __syncthreads();

        if (tid < 64) {
            const int row = tid;
            float* g = g_all + (size_t)(bl * 64 + row) * 20;
#pragma unroll
            for (int t = 0; t < 3; ++t) {
                const int base = (t == 0) ? 0 : (t == 1 ? 6 : 12);
                const int cnt  = (t == 2) ? 8 : 6;
                float m = -1e30f;
                for (int q = 0; q < cnt; ++q) m = fmaxf(m, logits[row][base + q]);
                float ex[8]; float sum = 0.f;
                for (int q = 0; q < cnt; ++q) { ex[q] = __expf(logits[row][base + q] - m); sum += ex[q]; }
                float inv = 1.f / sum;
                for (int q = 0; q < cnt; ++q) g[base + q] = ex[q] * inv;
            }
        }
    }
}

// ------- 256x256 bf16 GEMM: ring-4 BK=32, one-phase-ahead reads, DEPTH-8 counted vmcnt -------
// Change vs r15 (141.2 us): BOTH halves of tile t+3 staged in the U-phase; wait vmcnt(8).
// Safety (m135 oldest-first): at (t,U) after staging t+3, outstanding <= t+1's 4 +
// t+2's 4 + t+3's 4 = 12; vmcnt(8) drains the oldest 4 = ALL of t+1 -> (t,L)'s reads
// of buf t+1 are RAW-safe; t+2 and t+3 (8 loads) stay in flight across the barrier —
// the ring-4 maximum. Same at (t+1,U) for t+4 (guarantees t+2).
// Tails: no stage + t+3<NT -> vmcnt(4) (youngest 4 = t+3's; drains t+2);
//        t+2>=NT -> vmcnt(0). WAR: stage target (t+3)&3 not in readable {t,t+1,t+2};
// reads of that buffer drained >=1 barrier earlier.
__global__ __launch_bounds__(512, 2) void k_gemm_pipe(
    const unsigned short* __restrict__ A,
    const unsigned short* __restrict__ Bt,
    const float* __restrict__ bias,
    unsigned short* __restrict__ C,
    int M, int N, int K,
    long long sA, long long sB, long long sBias, long long sC, int e_base) {

    const int tid = threadIdx.x;
    const int lane = tid & 63, wid = tid >> 6;
    const int wr = wid >> 2, wc = wid & 3;       // 2 x 4 wave grid
    const int lr = lane & 15, lg = lane >> 4;

    const int nwg = gridDim.x;
    const int wg = blockIdx.x;
    const int swz = (wg & 7) * (nwg >> 3) + (wg >> 3);
    const int nx = N >> 8;
    const int my = M >> 8;
    const int bx = swz % nx;
    const int t1 = swz / nx;
    const int by = t1 % my;
    const int e  = t1 / my + e_base;

    A    += (size_t)((long long)e * sA);
    Bt   += (size_t)((long long)e * sB);
    bias += (size_t)((long long)e * sBias);
    C    += (size_t)((long long)e * sC);

    const int m0 = by * 256, n0 = bx * 256;

    __shared__ __align__(16) unsigned short lds[65536];   // 128 KiB
    char* ldsb = (char*)lds;

    const int srow = tid >> 2;
    const int scol = (((tid & 3) ^ ((tid >> 3) & 3)) * 8);
    const int sdst = tid * 16;

    auto stageA2 = [&](int t) {
        const int bb = (t & 3) * 32768;
        const unsigned short* s0 = A + (size_t)(m0 + srow) * K + (t << 5) + scol;
        __builtin_amdgcn_global_load_lds((gu32*)s0, (lu32*)(ldsb + bb + sdst), 16, 0, 0);
        __builtin_amdgcn_global_load_lds((gu32*)(s0 + (size_t)128 * K),
                                         (lu32*)(ldsb + bb + 8192 + sdst), 16, 0, 0);
    };
    auto stageB2 = [&](int t) {
        const int bb = (t & 3) * 32768 + 16384;
        const unsigned short* s0 = Bt + (size_t)(n0 + srow) * K + (t << 5) + scol;
        __builtin_amdgcn_global_load_lds((gu32*)s0, (lu32*)(ldsb + bb + sdst), 16, 0, 0);
        __builtin_amdgcn_global_load_lds((gu32*)(s0 + (size_t)128 * K),
                                         (lu32*)(ldsb + bb + 8192 + sdst), 16, 0, 0);
    };

    const int cblk = (lg ^ ((lr >> 1) & 3)) * 16;
    const int aoff = wr * 8192 + lr * 64 + cblk;
    const int boff = 16384 + (wc >> 1) * 8192 + (wc & 1) * 4096 + lr * 64 + cblk;

    f32x4 acc[8][4];
#pragma unroll
    for (int i = 0; i < 8; ++i)
#pragma unroll
        for (int j = 0; j < 4; ++j)
            acc[i][j] = f32x4{0.f, 0.f, 0.f, 0.f};

    auto mfma16 = [&](const bf16x8 (&fa)[4], const bf16x8 (&fb)[4], int rbase) {
        __builtin_amdgcn_s_setprio(1);
#pragma unroll
        for (int i = 0; i < 4; ++i)
#pragma unroll
            for (int j = 0; j < 4; ++j)
                acc[rbase + i][j] = __builtin_amdgcn_mfma_f32_16x16x32_bf16(
                    fa[i], fb[j], acc[rbase + i][j], 0, 0, 0);
        __builtin_amdgcn_s_setprio(0);
    };

    const int NT = K >> 5;   // 32 (divisible by 4)

    // prologue: stage tiles 0,1,2 (12 glds); vmcnt(8) -> tile 0 landed
    stageA2(0); stageB2(0); stageA2(1); stageB2(1); stageA2(2); stageB2(2);
    asm volatile("s_waitcnt vmcnt(8)" ::: "memory");
    asm volatile("s_barrier" ::: "memory");

    bf16x8 aU0[4], aL0[4], b0[4], aU1[4], aL1[4], b1v[4];
#pragma unroll
    for (int i = 0; i < 4; ++i) aU0[i] = *(const bf16x8*)(ldsb + aoff + i * 1024);
#pragma unroll
    for (int j = 0; j < 4; ++j) b0[j]  = *(const bf16x8*)(ldsb + boff + j * 1024);

#pragma unroll 2
    for (int t = 0; t < NT; t += 2) {
        const int bb0 = (t & 3) * 32768;
        const int bb1 = ((t + 1) & 3) * 32768;
        const int bb2 = ((t + 2) & 3) * 32768;

        // ---- phase (t,U): read L-frags(t); stage A+B(t+3); depth-8 wait; MFMA U(t) ----
#pragma unroll
        for (int i = 0; i < 4; ++i) aL0[i] = *(const bf16x8*)(ldsb + bb0 + aoff + (4 + i) * 1024);
        if (t + 3 < NT) { stageA2(t + 3); stageB2(t + 3);
                          asm volatile("s_waitcnt vmcnt(8)" ::: "memory"); }
        else if (t + 2 < NT) { asm volatile("s_waitcnt vmcnt(4)" ::: "memory"); }
        else                 { asm volatile("s_waitcnt vmcnt(0)" ::: "memory"); }
        asm volatile("s_barrier" ::: "memory");
        mfma16(aU0, b0, 0);

        // ---- phase (t,L): read U-frags(t+1); MFMA L(t) ----
#pragma unroll
        for (int i = 0; i < 4; ++i) aU1[i] = *(const bf16x8*)(ldsb + bb1 + aoff + i * 1024);
#pragma unroll
        for (int j = 0; j < 4; ++j) b1v[j] = *(const bf16x8*)(ldsb + bb1 + boff + j * 1024);
        asm volatile("s_barrier" ::: "memory");
        mfma16(aL0, b0, 4);

        // ---- phase (t+1,U): read L-frags(t+1); stage A+B(t+4); depth-8 wait; MFMA U(t+1) ----
#pragma unroll
        for (int i = 0; i < 4; ++i) aL1[i] = *(const bf16x8*)(ldsb + bb1 + aoff + (4 + i) * 1024);
        if (t + 4 < NT) { stageA2(t + 4); stageB2(t + 4);
                          asm volatile("s_waitcnt vmcnt(8)" ::: "memory"); }
        else if (t + 3 < NT) { asm volatile("s_waitcnt vmcnt(4)" ::: "memory"); }
        else                 { asm volatile("s_waitcnt vmcnt(0)" ::: "memory"); }
        asm volatile("s_barrier" ::: "memory");
        mfma16(aU1, b1v, 0);

        // ---- phase (t+1,L): read U-frags(t+2); MFMA L(t+1) ----
        if (t + 2 < NT) {
#pragma unroll
            for (int i = 0; i < 4; ++i) aU0[i] = *(const bf16x8*)(ldsb + bb2 + aoff + i * 1024);
#pragma unroll
            for (int j = 0; j < 4; ++j) b0[j]  = *(const bf16x8*)(ldsb + bb2 + boff + j * 1024);
        }
        asm volatile("s_barrier" ::: "memory");
        mfma16(aL1, b1v, 4);
    }

    // ---- epilogue: bias + relu -> LDS tile -> coalesced dwordx4 stores ----
    __syncthreads();
    unsigned short* ct = (unsigned short*)ldsb;
#pragma unroll
    for (int j = 0; j < 4; ++j) {
        const int nn = wc * 64 + j * 16 + lr;
        const float bv = bias[n0 + nn];
#pragma unroll
        for (int i = 0; i < 8; ++i) {
            const int mb = wr * 128 + i * 16 + lg * 4;
#pragma unroll
            for (int r = 0; r < 4; ++r) {
                float v = fmaxf(acc[i][j][r] + bv, 0.f);
                ct[(size_t)(mb + r) * 256 + nn] = f2bf(v);
            }
        }
    }
    __syncthreads();
#pragma unroll
    for (int it = 0; it < 16; ++it) {
        const int row = it * 16 + (tid >> 5);
        const int colE = (tid & 31) * 8;
        *(int4*)(&C[(size_t)(m0 + row) * N + n0 + colE]) =
            *(const int4*)(ldsb + it * 8192 + (size_t)tid * 16);
    }
}

// ---------------- combine: out[b][t][o], 8 o's per thread ----------------
__global__ __launch_bounds__(256) void k_combine(const unsigned short* __restrict__ eo,
                                                 const float* __restrict__ g_all,
                                                 float* __restrict__ out) {
    int idx8 = blockIdx.x * 256 + threadIdx.x;    // over B*O/8
    int b = idx8 >> 6;                            // O/8 = 64
    int o8 = (idx8 & 63) * 8;
    const float* g = g_all + (size_t)b * 20;
    float v[E_SZ][8];
#pragma unroll
    for (int e = 0; e < E_SZ; ++e) {
        const unsigned short* p = eo + (size_t)e * B_SZ * O_SZ + (size_t)b * O_SZ + o8;
        int4 u = *(const int4*)p;
        const unsigned short* us = (const unsigned short*)&u;
#pragma unroll
        for (int c = 0; c < 8; ++c) v[e][c] = bf2f(us[c]);
    }
    float r0[8], r1[8], r2[8];
#pragma unroll
    for (int c = 0; c < 8; ++c) {
        r0[c] = g[0] * v[0][c] + g[1] * v[1][c] + g[2] * v[4][c] + g[3] * v[5][c]
              + g[4] * v[6][c] + g[5] * v[7][c];
        r1[c] = g[6] * v[2][c] + g[7] * v[3][c] + g[8] * v[4][c] + g[9] * v[5][c]
              + g[10] * v[6][c] + g[11] * v[7][c];
        float s = 0.f;
#pragma unroll
        for (int e = 0; e < E_SZ; ++e) s += g[12 + e] * v[e][c];
        r2[c] = s;
    }
    size_t ob = (size_t)b * (3 * O_SZ) + o8;
    *(float4*)(out + ob)             = *(float4*)&r0[0];
    *(float4*)(out + ob + 4)         = *(float4*)&r0[4];
    *(float4*)(out + ob + O_SZ)      = *(float4*)&r1[0];
    *(float4*)(out + ob + O_SZ + 4)  = *(float4*)&r1[4];
    *(float4*)(out + ob + 2 * O_SZ)  = *(float4*)&r2[0];
    *(float4*)(out + ob + 2 * O_SZ + 4) = *(float4*)&r2[4];
}

extern "C" void kernel_launch(void* const* d_in, const int* in_sizes, int n_in,
                              void* d_out, int out_size, void* d_ws, size_t ws_size,
                              hipStream_t stream) {
    const float* x   = (const float*)d_in[0];
    const float* W1  = (const float*)d_in[1];
    const float* b1  = (const float*)d_in[2];
    const float* W2  = (const float*)d_in[3];
    const float* b2  = (const float*)d_in[4];
    const float* Wg  = (const float*)d_in[5];
    const float* Wgs = (const float*)d_in[6];
    float* out = (float*)d_out;

    char* ws = (char*)d_ws;
    const size_t SZ_XBF  = (size_t)B_SZ * D_SZ * 2;           // 16 MB
    const size_t SZ_W1T  = (size_t)E_SZ * H_SZ * D_SZ * 2;    // 16 MB
    const size_t SZ_W2T  = (size_t)E_SZ * O_SZ * H_SZ * 2;    // 8 MB
    const size_t SZ_EO   = (size_t)E_SZ * B_SZ * O_SZ * 2;    // 64 MB
    const size_t SZ_G    = (size_t)B_SZ * 20 * 4;             // 640 KB
    const size_t SZ_HBIG = (size_t)E_SZ * B_SZ * H_SZ * 2;    // 128 MB

    unsigned short* x_bf = (unsigned short*)ws;              ws += SZ_XBF;
    unsigned short* W1T  = (unsigned short*)ws;              ws += SZ_W1T;
    unsigned short* W2T  = (unsigned short*)ws;              ws += SZ_W2T;
    unsigned short* eo   = (unsigned short*)ws;              ws += SZ_EO;
    float* g_all         = (float*)ws;                       ws += SZ_G;
    unsigned short* h_buf = (unsigned short*)ws;

    const size_t fixed = SZ_XBF + SZ_W1T + SZ_W2T + SZ_EO + SZ_G;
    const bool big = ws_size >= fixed + SZ_HBIG;

    // 1) fused prep: convert | transposes | gates  (one launch)
    k_prep<<<5248, 512, 0, stream>>>(x, W1, W2, Wg, Wgs, x_bf, W1T, W2T, g_all);

    // 2) expert GEMMs (256x256 tiles; flat 1D grids, all % 8 == 0)
    if (big) {
        k_gemm_pipe<<<(H_SZ / 256) * (B_SZ / 256) * E_SZ, 512, 0, stream>>>(
            x_bf, W1T, b1, h_buf, B_SZ, H_SZ, D_SZ,
            0LL, (long long)H_SZ * D_SZ, (long long)H_SZ, (long long)B_SZ * H_SZ, 0);
        k_gemm_pipe<<<(O_SZ / 256) * (B_SZ / 256) * E_SZ, 512, 0, stream>>>(
            h_buf, W2T, b2, eo, B_SZ, O_SZ, H_SZ,
            (long long)B_SZ * H_SZ, (long long)O_SZ * H_SZ, (long long)O_SZ, (long long)B_SZ * O_SZ, 0);
    } else {
        for (int e = 0; e < E_SZ; ++e) {
            k_gemm_pipe<<<(H_SZ / 256) * (B_SZ / 256), 512, 0, stream>>>(
                x_bf, W1T, b1, h_buf, B_SZ, H_SZ, D_SZ,
                0LL, (long long)H_SZ * D_SZ, (long long)H_SZ, 0LL, e);
            k_gemm_pipe<<<(O_SZ / 256) * (B_SZ / 256), 512, 0, stream>>>(
                h_buf, W2T, b2, eo, B_SZ, O_SZ, H_SZ,
                0LL, (long long)O_SZ * H_SZ, (long long)O_SZ, (long long)B_SZ * O_SZ, e);
        }
    }

    // 3) combine
    k_combine<<<(B_SZ * O_SZ / 8) / 256, 256, 0, stream>>>(eo, g_all, out);
}